// Round 12
// baseline (227.167 us; speedup 1.0000x reference)
//
#include <hip/hip_runtime.h>

#define B_ 4
#define N_ 2048
#define D_ 1024
#define H_ 16
#define HD_ 64
// SCALE * log2(e): softmax runs in exp2 domain
#define QSCALE_ 0.18033688011112042f

typedef __bf16 bf16x8 __attribute__((ext_vector_type(8)));
typedef float f32x4 __attribute__((ext_vector_type(4)));

#if __has_builtin(__builtin_amdgcn_exp2f)
#define EXP2(x) __builtin_amdgcn_exp2f(x)
#else
#define EXP2(x) exp2f(x)
#endif

__device__ __forceinline__ f32x4 mfma16(bf16x8 a, bf16x8 b, f32x4 c) {
    return __builtin_amdgcn_mfma_f32_16x16x32_bf16(a, b, c, 0, 0, 0);
}

__device__ __forceinline__ void gload16(const void* g, void* l) {
    __builtin_amdgcn_global_load_lds(
        (const __attribute__((address_space(1))) void*)g,
        (__attribute__((address_space(3))) void*)l, 16, 0, 0);
}

__device__ __forceinline__ unsigned pack2(float x, float y) {
    __bf16 a = (__bf16)x, b = (__bf16)y;
    unsigned ua = __builtin_bit_cast(unsigned short, a);
    unsigned ub = __builtin_bit_cast(unsigned short, b);
    return ua | (ub << 16);
}

// ---------------------------------------------------------------- fused pre-pass (big path)
__global__ __launch_bounds__(256) void pre_kernel(
    const float* __restrict__ q, const float* __restrict__ k, const float* __restrict__ v,
    __bf16* __restrict__ xb,
    const float* __restrict__ W0, const float* __restrict__ W1,
    const float* __restrict__ W2, const float* __restrict__ W3,
    __bf16* __restrict__ T0, __bf16* __restrict__ T1,
    __bf16* __restrict__ T2, __bf16* __restrict__ T3,
    const float* __restrict__ pe, const int* __restrict__ mask,
    unsigned* __restrict__ cstab, float* __restrict__ maskf)
{
    const int y = blockIdx.y;
    const int x = blockIdx.x;
    const int t = threadIdx.x;

    if (y < 3) {
        const float* src = (y == 0) ? q : (y == 1) ? k : v;
        __bf16* dst = xb + (size_t)y * 8388608;
        size_t i = ((size_t)x * 256 + t) * 8;
        float4 a = *(const float4*)(src + i);
        float4 b = *(const float4*)(src + i + 4);
        bf16x8 o;
        o[0] = (__bf16)a.x; o[1] = (__bf16)a.y; o[2] = (__bf16)a.z; o[3] = (__bf16)a.w;
        o[4] = (__bf16)b.x; o[5] = (__bf16)b.y; o[6] = (__bf16)b.z; o[7] = (__bf16)b.w;
        *(bf16x8*)(dst + i) = o;
        return;
    }
    if (x < 1024) {
        const int which = x >> 8;
        const float* W = (which == 0) ? W0 : (which == 1) ? W1 : (which == 2) ? W2 : W3;
        __bf16* Wt = (which == 0) ? T0 : (which == 1) ? T1 : (which == 2) ? T2 : T3;
        const int k0 = ((x >> 4) & 15) * 64, n0 = (x & 15) * 64;
        __shared__ float T[64][65];
#pragma unroll
        for (int i = 0; i < 4; ++i) {
            int row = i * 16 + (t >> 4);
            int c4 = (t & 15) * 4;
            float4 vv = *(const float4*)(W + (size_t)(k0 + row) * D_ + n0 + c4);
            T[row][c4] = vv.x; T[row][c4 + 1] = vv.y; T[row][c4 + 2] = vv.z; T[row][c4 + 3] = vv.w;
        }
        __syncthreads();
#pragma unroll
        for (int i = 0; i < 2; ++i) {
            int task = i * 256 + t;
            int nrow = task >> 3, ks = task & 7;
            bf16x8 o;
#pragma unroll
            for (int e = 0; e < 8; ++e) o[e] = (__bf16)T[ks * 8 + e][nrow];
            *(bf16x8*)(Wt + (size_t)(n0 + nrow) * D_ + k0 + ks * 8) = o;
        }
        return;
    }
    if (x < 1568) {
        int i = (x - 1024) * 256 + t;
        if (i < N_ * HD_) {
            float vv = pe[i];
            __bf16 cb = (__bf16)cosf(vv), sb = (__bf16)sinf(vv);
            unsigned cu = __builtin_bit_cast(unsigned short, cb);
            unsigned su = __builtin_bit_cast(unsigned short, sb);
            cstab[i] = cu | (su << 16);
        }
        if (i < B_ * N_) maskf[i] = mask[i] ? -1e30f : 0.0f;
    }
}

// ---------------------------------------------------------------- prep (fallback path)
__global__ void prep_kernel(const float* __restrict__ pe, const int* __restrict__ mask,
                            unsigned* __restrict__ cstab, float* __restrict__ maskf) {
    int i = blockIdx.x * 256 + threadIdx.x;
    if (i < N_ * HD_) {
        float v = pe[i];
        __bf16 cb = (__bf16)cosf(v), sb = (__bf16)sinf(v);
        unsigned cu = __builtin_bit_cast(unsigned short, cb);
        unsigned su = __builtin_bit_cast(unsigned short, sb);
        cstab[i] = cu | (su << 16);
    }
    if (i < B_ * N_) maskf[i] = mask[i] ? -1e30f : 0.0f;
}

// ---------------------------------------------------------------- weight transpose (fallback)
__global__ __launch_bounds__(256) void tw_kernel(const float* __restrict__ W, __bf16* __restrict__ Wt) {
    __shared__ float T[64][65];
    const int k0 = blockIdx.x * 64, n0 = blockIdx.y * 64;
    const int t = threadIdx.x;
#pragma unroll
    for (int i = 0; i < 4; ++i) {
        int row = i * 16 + (t >> 4);
        int c4 = (t & 15) * 4;
        float4 v = *(const float4*)(W + (size_t)(k0 + row) * D_ + n0 + c4);
        T[row][c4] = v.x; T[row][c4 + 1] = v.y; T[row][c4 + 2] = v.z; T[row][c4 + 3] = v.w;
    }
    __syncthreads();
#pragma unroll
    for (int i = 0; i < 2; ++i) {
        int task = i * 256 + t;
        int nrow = task >> 3, ks = task & 7;
        bf16x8 o;
#pragma unroll
        for (int e = 0; e < 8; ++e) o[e] = (__bf16)T[ks * 8 + e][nrow];
        *(bf16x8*)(Wt + (size_t)(n0 + nrow) * D_ + k0 + ks * 8) = o;
    }
}

// ---------------------------------------------------------------- weight transpose x3 (fallback)
__global__ __launch_bounds__(256) void tw3_kernel(
    const float* __restrict__ W0, const float* __restrict__ W1, const float* __restrict__ W2,
    __bf16* __restrict__ T0, __bf16* __restrict__ T1, __bf16* __restrict__ T2)
{
    const float* W = (blockIdx.z == 0) ? W0 : (blockIdx.z == 1) ? W1 : W2;
    __bf16* Wt = (blockIdx.z == 0) ? T0 : (blockIdx.z == 1) ? T1 : T2;
    __shared__ float T[64][65];
    const int k0 = blockIdx.x * 64, n0 = blockIdx.y * 64;
    const int t = threadIdx.x;
#pragma unroll
    for (int i = 0; i < 4; ++i) {
        int row = i * 16 + (t >> 4);
        int c4 = (t & 15) * 4;
        float4 v = *(const float4*)(W + (size_t)(k0 + row) * D_ + n0 + c4);
        T[row][c4] = v.x; T[row][c4 + 1] = v.y; T[row][c4 + 2] = v.z; T[row][c4 + 3] = v.w;
    }
    __syncthreads();
#pragma unroll
    for (int i = 0; i < 2; ++i) {
        int task = i * 256 + t;
        int nrow = task >> 3, ks = task & 7;
        bf16x8 o;
#pragma unroll
        for (int e = 0; e < 8; ++e) o[e] = (__bf16)T[ks * 8 + e][nrow];
        *(bf16x8*)(Wt + (size_t)(n0 + nrow) * D_ + k0 + ks * 8) = o;
    }
}

// ---------------------------------------------------------------- fused QKV projection v6 (big path)
__global__ __launch_bounds__(256) void proj_v6(
    const __bf16* __restrict__ Xb,   // [3][8192][1024] bf16
    const __bf16* __restrict__ WtQ, const __bf16* __restrict__ WtK, const __bf16* __restrict__ WtV,
    const float* __restrict__ bQ, const float* __restrict__ bK, const float* __restrict__ bV,
    const unsigned* __restrict__ cstab,
    __bf16* __restrict__ dq, __bf16* __restrict__ dk, __bf16* __restrict__ dv)
{
    __shared__ __align__(16) char smem[35072];     // As 16K | Bs 16K ; mode2 epi: T[128][136]
    __bf16* As = (__bf16*)smem;
    __bf16* Bs = (__bf16*)(smem + 16384);

    const int which = blockIdx.y >> 3;
    const __bf16* X   = Xb + (size_t)which * 8388608;
    const __bf16* Wt  = (which == 0) ? WtQ : (which == 1) ? WtK : WtV;
    const float* bias = (which == 0) ? bQ  : (which == 1) ? bK  : bV;
    __bf16* dst       = (which == 0) ? dq  : (which == 1) ? dk  : dv;
    const int mode = which;

    const int tid = threadIdx.x;
    const int lane = tid & 63, w = tid >> 6;
    const int wr = w >> 1, wc = w & 1;
    const int r16 = lane & 15, g = lane >> 4;
    const int m0 = blockIdx.x * 128;
    const int n0 = (blockIdx.y & 7) * 128;
    const int srow8 = tid >> 3, slot = tid & 7;

    f32x4 acc[4][4];
#pragma unroll
    for (int m = 0; m < 4; ++m)
#pragma unroll
        for (int n = 0; n < 4; ++n) acc[m][n] = (f32x4){0.f, 0.f, 0.f, 0.f};

    for (int kt = 0; kt < 16; ++kt) {
#pragma unroll
        for (int j = 0; j < 4; ++j) {
            int row = j * 32 + srow8;
            const char* srcA = (const char*)X + ((size_t)(m0 + row) * D_ + kt * 64) * 2
                               + ((slot ^ (row & 7)) << 4);
            gload16(srcA, (char*)As + j * 4096 + w * 1024);
            const char* srcB = (const char*)Wt + ((size_t)(n0 + row) * D_ + kt * 64) * 2
                               + ((slot ^ (row & 7)) << 4);
            gload16(srcB, (char*)Bs + j * 4096 + w * 1024);
        }
        __syncthreads();
#pragma unroll
        for (int kk = 0; kk < 2; ++kk) {
            bf16x8 aF[4], bF[4];
#pragma unroll
            for (int m = 0; m < 4; ++m) {
                int row = wr * 64 + m * 16 + r16;
                aF[m] = *(const bf16x8*)((char*)As + row * 128 + (((kk * 4 + g) ^ (row & 7)) << 4));
            }
#pragma unroll
            for (int n = 0; n < 4; ++n) {
                int row = wc * 64 + n * 16 + r16;
                bF[n] = *(const bf16x8*)((char*)Bs + row * 128 + (((kk * 4 + g) ^ (row & 7)) << 4));
            }
#pragma unroll
            for (int m = 0; m < 4; ++m)
#pragma unroll
                for (int n = 0; n < 4; ++n)
                    acc[m][n] = mfma16(aF[m], bF[n], acc[m][n]);
        }
        __syncthreads();
    }

    if (mode <= 1) {
#pragma unroll
        for (int m = 0; m < 4; ++m)
#pragma unroll
            for (int n = 0; n < 4; ++n) {
                int col = n0 + wc * 64 + n * 16 + r16;
                int h = col >> 6, hd = col & 63;
#pragma unroll
                for (int j = 0; j < 4; ++j) {
                    int bn = m0 + wr * 64 + m * 16 + g * 4 + j;
                    int np = bn & (N_ - 1), b = bn >> 11;
                    float val = acc[m][n][j] + bias[col];
                    if (mode == 0) val *= QSCALE_;
                    float other = __shfl_xor(val, 1);
                    unsigned cs = cstab[np * HD_ + hd];
                    float c = __uint_as_float(cs << 16);
                    float sn = __uint_as_float(cs & 0xffff0000u);
                    val = val * c + ((col & 1) ? other : -other) * sn;
                    dst[((size_t)(b * H_ + h) * N_ + np) * HD_ + hd] = (__bf16)val;
                }
            }
    } else {
        __bf16* T = (__bf16*)smem;   // [128][136]
        __syncthreads();
#pragma unroll
        for (int m = 0; m < 4; ++m)
#pragma unroll
            for (int n = 0; n < 4; ++n) {
                int c = wc * 64 + n * 16 + r16;
                float bs = bias[n0 + c];
#pragma unroll
                for (int j = 0; j < 4; ++j) {
                    int sr = wr * 64 + m * 16 + g * 4 + j;
                    T[c * 136 + sr] = (__bf16)(acc[m][n][j] + bs);
                }
            }
        __syncthreads();
        const int b = m0 >> 11, np0 = m0 & (N_ - 1);
#pragma unroll
        for (int i = 0; i < 8; ++i) {
            int task = i * 256 + tid;
            int trow = task >> 4, ch = task & 15;
            int colg = n0 + trow;
            int h = colg >> 6, hd = colg & 63;
            bf16x8 vv = *(const bf16x8*)&T[trow * 136 + ch * 8];
            *(bf16x8*)(dst + (((size_t)(b * H_ + h) * HD_ + hd) * N_ + np0 + ch * 8)) = vv;
        }
    }
}

// ---------------------------------------------------------------- fused QKV projection v5 (fallback)
__global__ __launch_bounds__(256) void proj_v5(
    const float* __restrict__ Xq, const float* __restrict__ Xk, const float* __restrict__ Xv,
    const __bf16* __restrict__ WtQ, const __bf16* __restrict__ WtK, const __bf16* __restrict__ WtV,
    const float* __restrict__ bQ, const float* __restrict__ bK, const float* __restrict__ bV,
    const unsigned* __restrict__ cstab,
    __bf16* __restrict__ dq, __bf16* __restrict__ dk, __bf16* __restrict__ dv)
{
    __shared__ __align__(16) char smem[35072];
    __bf16* As = (__bf16*)smem;
    __bf16* Bs = (__bf16*)(smem + 16384);

    const int which = blockIdx.y >> 3;
    const float* X    = (which == 0) ? Xq  : (which == 1) ? Xk  : Xv;
    const __bf16* Wt  = (which == 0) ? WtQ : (which == 1) ? WtK : WtV;
    const float* bias = (which == 0) ? bQ  : (which == 1) ? bK  : bV;
    __bf16* dst       = (which == 0) ? dq  : (which == 1) ? dk  : dv;
    const int mode = which;

    const int tid = threadIdx.x;
    const int lane = tid & 63, w = tid >> 6;
    const int wr = w >> 1, wc = w & 1;
    const int r16 = lane & 15, g = lane >> 4;
    const int m0 = blockIdx.x * 128;
    const int n0 = (blockIdx.y & 7) * 128;
    const int srow8 = tid >> 3, slot = tid & 7;

    f32x4 acc[4][4];
#pragma unroll
    for (int m = 0; m < 4; ++m)
#pragma unroll
        for (int n = 0; n < 4; ++n) acc[m][n] = (f32x4){0.f, 0.f, 0.f, 0.f};

    for (int kt = 0; kt < 16; ++kt) {
        float4 va0[4], va1[4];
#pragma unroll
        for (int i = 0; i < 4; ++i) {
            int row = i * 32 + srow8;
            const float* s = X + (size_t)(m0 + row) * D_ + kt * 64 + slot * 8;
            va0[i] = *(const float4*)s;
            va1[i] = *(const float4*)(s + 4);
        }
#pragma unroll
        for (int j = 0; j < 4; ++j) {
            int row = j * 32 + srow8;
            const char* src = (const char*)Wt + ((size_t)(n0 + row) * D_ + kt * 64) * 2
                              + ((slot ^ (row & 7)) << 4);
            gload16(src, (char*)Bs + j * 4096 + w * 1024);
        }
#pragma unroll
        for (int i = 0; i < 4; ++i) {
            int row = i * 32 + srow8;
            bf16x8 bv;
            bv[0] = (__bf16)va0[i].x; bv[1] = (__bf16)va0[i].y;
            bv[2] = (__bf16)va0[i].z; bv[3] = (__bf16)va0[i].w;
            bv[4] = (__bf16)va1[i].x; bv[5] = (__bf16)va1[i].y;
            bv[6] = (__bf16)va1[i].z; bv[7] = (__bf16)va1[i].w;
            *(bf16x8*)((char*)As + row * 128 + ((slot ^ (row & 7)) << 4)) = bv;
        }
        __syncthreads();
#pragma unroll
        for (int kk = 0; kk < 2; ++kk) {
            bf16x8 aF[4], bF[4];
#pragma unroll
            for (int m = 0; m < 4; ++m) {
                int row = wr * 64 + m * 16 + r16;
                aF[m] = *(const bf16x8*)((char*)As + row * 128 + (((kk * 4 + g) ^ (row & 7)) << 4));
            }
#pragma unroll
            for (int n = 0; n < 4; ++n) {
                int row = wc * 64 + n * 16 + r16;
                bF[n] = *(const bf16x8*)((char*)Bs + row * 128 + (((kk * 4 + g) ^ (row & 7)) << 4));
            }
#pragma unroll
            for (int m = 0; m < 4; ++m)
#pragma unroll
                for (int n = 0; n < 4; ++n)
                    acc[m][n] = mfma16(aF[m], bF[n], acc[m][n]);
        }
        __syncthreads();
    }

    if (mode <= 1) {
#pragma unroll
        for (int m = 0; m < 4; ++m)
#pragma unroll
            for (int n = 0; n < 4; ++n) {
                int col = n0 + wc * 64 + n * 16 + r16;
                int h = col >> 6, hd = col & 63;
#pragma unroll
                for (int j = 0; j < 4; ++j) {
                    int bn = m0 + wr * 64 + m * 16 + g * 4 + j;
                    int np = bn & (N_ - 1), b = bn >> 11;
                    float val = acc[m][n][j] + bias[col];
                    if (mode == 0) val *= QSCALE_;
                    float other = __shfl_xor(val, 1);
                    unsigned cs = cstab[np * HD_ + hd];
                    float c = __uint_as_float(cs << 16);
                    float sn = __uint_as_float(cs & 0xffff0000u);
                    val = val * c + ((col & 1) ? other : -other) * sn;
                    dst[((size_t)(b * H_ + h) * N_ + np) * HD_ + hd] = (__bf16)val;
                }
            }
    } else {
        __bf16* T = (__bf16*)smem;   // [128][136]
        __syncthreads();
#pragma unroll
        for (int m = 0; m < 4; ++m)
#pragma unroll
            for (int n = 0; n < 4; ++n) {
                int c = wc * 64 + n * 16 + r16;
                float bs = bias[n0 + c];
#pragma unroll
                for (int j = 0; j < 4; ++j) {
                    int sr = wr * 64 + m * 16 + g * 4 + j;
                    T[c * 136 + sr] = (__bf16)(acc[m][n][j] + bs);
                }
            }
        __syncthreads();
        const int b = m0 >> 11, np0 = m0 & (N_ - 1);
#pragma unroll
        for (int i = 0; i < 8; ++i) {
            int task = i * 256 + tid;
            int trow = task >> 4, ch = task & 15;
            int colg = n0 + trow;
            int h = colg >> 6, hd = colg & 63;
            bf16x8 vv = *(const bf16x8*)&T[trow * 136 + ch * 8];
            *(bf16x8*)(dst + (((size_t)(b * H_ + h) * HD_ + hd) * N_ + np0 + ch * 8)) = vv;
        }
    }
}

// ---------------------------------------------------------------- flash attention v9
// v8 schedule, QBLK=128 (8 waves x 16 q-rows): 1024 blocks -> 3 blocks/CU
// (24 waves/CU, +50% TLP); P-writes merged to ds_write_b64.
__global__ __launch_bounds__(512, 4) void attn_v9(
    const __bf16* __restrict__ qws, const __bf16* __restrict__ kws,
    const __bf16* __restrict__ vtws, const float* __restrict__ maskf,
    __bf16* __restrict__ ows)
{
    __shared__ __align__(16) __bf16 Ks0[4096], Ks1[4096];   // [seq 64][hd 64] swizzled
    __shared__ __align__(16) __bf16 Vs0[4096], Vs1[4096];   // [hd 64][seq 64] swizzled
    __shared__ __align__(16) char Pbuf[16384];              // 8 waves x [16 q][64 k] bf16

    const int tid = threadIdx.x;
    const int lane = tid & 63, w = tid >> 6;
    const int r16 = lane & 15, g = lane >> 4;

    // XCD swizzle: 1024 blocks -> 8 chunks of 128 (8 bh each), chunk c on XCD c.
    const int lid = blockIdx.x;
    const int virt = (lid & 7) * 128 + (lid >> 3);
    const int bh = virt >> 4;
    const int b = bh >> 4, h = bh & 15;
    const int q0 = (virt & 15) * 128;
    const int srow8 = tid >> 3, slot = tid & 7;   // srow8 in [0,64)

    bf16x8 qF0, qF1;
    {
        const __bf16* qb = qws + ((size_t)bh * N_ + q0 + w * 16 + r16) * HD_ + g * 8;
        qF0 = *(const bf16x8*)qb;
        qF1 = *(const bf16x8*)(qb + 32);
    }

    bf16x8 onesF;
#pragma unroll
    for (int e = 0; e < 8; ++e) onesF[e] = (__bf16)1.0f;

    const char* kbase = (const char*)(kws + (size_t)bh * N_ * HD_);
    const char* vbase = (const char*)(vtws + (size_t)bh * HD_ * N_);
    const float* mbase = maskf + b * N_;
    char* Pw = Pbuf + w * 2048;

    f32x4 o[4];
    f32x4 lacc = (f32x4){0.f, 0.f, 0.f, 0.f};
#pragma unroll
    for (int n = 0; n < 4; ++n) o[n] = (f32x4){0.f, 0.f, 0.f, 0.f};

// 512 threads: each issues exactly 1 K-row-slot + 1 V-row-slot gload16.
// Wave w's lanes cover rows [w*8, w*8+8) -> LDS chunk w*1024 (linear dest).
#define STAGE_(KD, VD, kt) {                                                          \
    gload16(kbase + (size_t)((kt) * 64 + srow8) * 128 + ((slot ^ (srow8 & 7)) << 4),  \
            (char*)(KD) + w * 1024);                                                  \
    gload16(vbase + (size_t)srow8 * (N_ * 2) + (kt) * 128 + ((slot ^ (srow8 & 7)) << 4), \
            (char*)(VD) + w * 1024);                                                  \
    }

#define TILE_(KB, VB, KN, VN, kt) {                                                   \
    if ((kt) + 1 < 32) STAGE_(KN, VN, (kt) + 1);                                      \
    f32x4 s[4];                                                                       \
    _Pragma("unroll")                                                                 \
    for (int n = 0; n < 4; ++n)                                                       \
        s[n] = *(const f32x4*)(mbase + (kt) * 64 + n * 16 + g * 4);                   \
    __builtin_amdgcn_s_setprio(1);                                                    \
    _Pragma("unroll")                                                                 \
    for (int n = 0; n < 4; ++n) {                                                     \
        int row = n * 16 + r16;                                                       \
        bf16x8 kF0 = *(const bf16x8*)((const char*)(KB) + row * 128 + ((g ^ (row & 7)) << 4));        \
        bf16x8 kF1 = *(const bf16x8*)((const char*)(KB) + row * 128 + (((4 + g) ^ (row & 7)) << 4));  \
        s[n] = mfma16(kF0, qF0, s[n]);                                                \
        s[n] = mfma16(kF1, qF1, s[n]);                                                \
    }                                                                                 \
    __builtin_amdgcn_s_setprio(0);                                                    \
    bf16x8 pF[2];                                                                     \
    _Pragma("unroll")                                                                 \
    for (int n = 0; n < 4; ++n) {                                                     \
        int u0 = ((n * 2 + (g >> 1)) ^ (r16 & 7));                                    \
        unsigned lo = pack2(EXP2(s[n][0]), EXP2(s[n][1]));                            \
        unsigned hi = pack2(EXP2(s[n][2]), EXP2(s[n][3]));                            \
        *(unsigned long long*)(Pw + r16 * 128 + u0 * 16 + (g & 1) * 8) =              \
            ((unsigned long long)hi << 32) | lo;                                      \
    }                                                                                 \
    _Pragma("unroll")                                                                 \
    for (int kk = 0; kk < 2; ++kk)                                                    \
        pF[kk] = *(const bf16x8*)(Pw + r16 * 128 + (((kk * 4 + g) ^ (r16 & 7)) << 4)); \
    lacc = mfma16(onesF, pF[0], lacc);                                                \
    lacc = mfma16(onesF, pF[1], lacc);                                                \
    __builtin_amdgcn_s_setprio(1);                                                    \
    _Pragma("unroll")                                                                 \
    for (int n = 0; n < 4; ++n) {                                                     \
        int row = n * 16 + r16;                                                       \
        bf16x8 vF0 = *(const bf16x8*)((const char*)(VB) + row * 128 + ((g ^ (row & 7)) << 4));        \
        bf16x8 vF1 = *(const bf16x8*)((const char*)(VB) + row * 128 + (((4 + g) ^ (row & 7)) << 4));  \
        o[n] = mfma16(vF0, pF[0], o[n]);                                              \
        o[n] = mfma16(vF1, pF[1], o[n]);                                              \
    }                                                                                 \
    __builtin_amdgcn_s_setprio(0);                                                    \
    __syncthreads(); }

    STAGE_(Ks0, Vs0, 0);
    __syncthreads();

    for (int kt = 0; kt < 32; kt += 2) {
        TILE_(Ks0, Vs0, Ks1, Vs1, kt);
        TILE_(Ks1, Vs1, Ks0, Vs0, kt + 1);
    }
#undef TILE_
#undef STAGE_

    // epilogue: normalize, transpose O^T->O via Pbuf, 16B stores
    {
        float inv = 1.0f / lacc[0];
#pragma unroll
        for (int n = 0; n < 4; ++n) {
            int u0 = ((n * 2 + (g >> 1)) ^ (r16 & 7));
            unsigned lo = pack2(o[n][0] * inv, o[n][1] * inv);
            unsigned hi = pack2(o[n][2] * inv, o[n][3] * inv);
            *(unsigned long long*)(Pw + r16 * 128 + u0 * 16 + (g & 1) * 8) =
                ((unsigned long long)hi << 32) | lo;
        }
        int qrow = q0 + w * 16 + r16;
#pragma unroll
        for (int kk = 0; kk < 2; ++kk) {
            bf16x8 v = *(const bf16x8*)(Pw + r16 * 128 + (((kk * 4 + g) ^ (r16 & 7)) << 4));
            *(bf16x8*)(ows + ((size_t)(b * N_ + qrow)) * D_ + h * HD_ + kk * 32 + g * 8) = v;
        }
    }
}

// ---------------------------------------------------------------- output GEMM
__global__ __launch_bounds__(256) void gemm_out_v2(
    const __bf16* __restrict__ A, const __bf16* __restrict__ Wt,
    const float* __restrict__ bias, float* __restrict__ out)
{
    __shared__ __align__(16) __bf16 As[8192], Bs[8192];

    const int tid = threadIdx.x;
    const int lane = tid & 63, w = tid >> 6;
    const int wr = w >> 1, wc = w & 1;
    const int r16 = lane & 15, g = lane >> 4;
    const int m0 = blockIdx.x * 128;
    const int n0 = blockIdx.y * 128;
    const int srow8 = tid >> 3, slot = tid & 7;

    f32x4 acc[4][4];
#pragma unroll
    for (int m = 0; m < 4; ++m)
#pragma unroll
        for (int n = 0; n < 4; ++n) acc[m][n] = (f32x4){0.f, 0.f, 0.f, 0.f};

    for (int kt = 0; kt < 16; ++kt) {
#pragma unroll
        for (int j = 0; j < 4; ++j) {
            int row = j * 32 + srow8;
            const char* srcA = (const char*)A + ((size_t)(m0 + row) * D_ + kt * 64) * 2
                               + ((slot ^ (row & 7)) << 4);
            gload16(srcA, (char*)As + j * 4096 + w * 1024);
            const char* srcB = (const char*)Wt + ((size_t)(n0 + row) * D_ + kt * 64) * 2
                               + ((slot ^ (row & 7)) << 4);
            gload16(srcB, (char*)Bs + j * 4096 + w * 1024);
        }
        __syncthreads();
#pragma unroll
        for (int kk = 0; kk < 2; ++kk) {
            bf16x8 aF[4], bF[4];
#pragma unroll
            for (int m = 0; m < 4; ++m) {
                int row = wr * 64 + m * 16 + r16;
                aF[m] = *(const bf16x8*)((char*)As + row * 128 + (((kk * 4 + g) ^ (row & 7)) << 4));
            }
#pragma unroll
            for (int n = 0; n < 4; ++n) {
                int row = wc * 64 + n * 16 + r16;
                bF[n] = *(const bf16x8*)((char*)Bs + row * 128 + (((kk * 4 + g) ^ (row & 7)) << 4));
            }
#pragma unroll
            for (int m = 0; m < 4; ++m)
#pragma unroll
                for (int n = 0; n < 4; ++n)
                    acc[m][n] = mfma16(aF[m], bF[n], acc[m][n]);
        }
        __syncthreads();
    }

#pragma unroll
    for (int m = 0; m < 4; ++m)
#pragma unroll
        for (int n = 0; n < 4; ++n) {
            int col = n0 + wc * 64 + n * 16 + r16;
            float bs = bias[col];
#pragma unroll
            for (int j = 0; j < 4; ++j) {
                int bn = m0 + wr * 64 + m * 16 + g * 4 + j;
                out[(size_t)bn * D_ + col] = acc[m][n][j] + bs;
            }
        }
}

// ---------------------------------------------------------------- launcher
extern "C" void kernel_launch(void* const* d_in, const int* in_sizes, int n_in,
                              void* d_out, int out_size, void* d_ws, size_t ws_size,
                              hipStream_t stream)
{
    const float* query = (const float*)d_in[0];
    const float* key   = (const float*)d_in[1];
    const float* value = (const float*)d_in[2];
    const int* mask    = (const int*)d_in[3];
    const float* pos_enc = (const float*)d_in[4];
    const float* Wq = (const float*)d_in[5];
    const float* bq = (const float*)d_in[6];
    const float* Wk = (const float*)d_in[7];
    const float* bk = (const float*)d_in[8];
    const float* Wv = (const float*)d_in[9];
    const float* bv = (const float*)d_in[10];
    const float* Wo = (const float*)d_in[11];
    const float* bo = (const float*)d_in[12];
    float* out = (float*)d_out;

    char* ws = (char*)d_ws;
    const size_t MB16 = (size_t)16 * 1024 * 1024;
    const size_t MB2  = (size_t)2 * 1024 * 1024;
    const size_t need_big = 3 * MB16 + 4 * MB16 + 4 * MB2 + 524288 + 32768;
    const size_t need_small = 4 * MB16 + 524288 + 32768;

    if (ws_size >= need_big) {
        __bf16* Xb    = (__bf16*)(ws);                     // 48 MB
        __bf16* qws   = (__bf16*)(ws + 3 * MB16);
        __bf16* kws   = (__bf16*)(ws + 4 * MB16);
        __bf16* vtws  = (__bf16*)(ws + 5 * MB16);
        __bf16* ows   = (__bf16*)(ws + 6 * MB16);
        __bf16* wtQ   = (__bf16*)(ws + 7 * MB16);
        __bf16* wtK   = (__bf16*)(ws + 7 * MB16 + MB2);
        __bf16* wtV   = (__bf16*)(ws + 7 * MB16 + 2 * MB2);
        __bf16* wtO   = (__bf16*)(ws + 7 * MB16 + 3 * MB2);
        unsigned* cstab = (unsigned*)(ws + 7 * MB16 + 4 * MB2);
        float* maskf  = (float*)(ws + 7 * MB16 + 4 * MB2 + 524288);

        hipLaunchKernelGGL(pre_kernel, dim3(4096, 4), dim3(256), 0, stream,
                           query, key, value, Xb, Wq, Wk, Wv, Wo, wtQ, wtK, wtV, wtO,
                           pos_enc, mask, cstab, maskf);
        hipLaunchKernelGGL(proj_v6, dim3(64, 24), dim3(256), 0, stream,
                           Xb, wtQ, wtK, wtV, bq, bk, bv, cstab, qws, kws, vtws);
        hipLaunchKernelGGL(attn_v9, dim3(1024), dim3(512), 0, stream,
                           qws, kws, vtws, maskf, ows);
        hipLaunchKernelGGL(gemm_out_v2, dim3(64, 8), dim3(256), 0, stream, ows, wtO, bo, out);
    } else {
        if (ws_size < need_small) return;
        __bf16* qws   = (__bf16*)(ws);
        __bf16* kws   = (__bf16*)(ws + MB16);
        __bf16* vtws  = (__bf16*)(ws + 2 * MB16);
        __bf16* ows   = (__bf16*)(ws + 3 * MB16);
        unsigned* cstab = (unsigned*)(ws + 4 * MB16);
        float* maskf  = (float*)(ws + 4 * MB16 + 524288);
        __bf16* wtQ   = (__bf16*)(ws + 3 * MB16);
        __bf16* wtK   = wtQ + (size_t)D_ * D_;
        __bf16* wtV   = wtK + (size_t)D_ * D_;
        __bf16* wtO   = (__bf16*)(ws);

        hipLaunchKernelGGL(prep_kernel, dim3(512), dim3(256), 0, stream, pos_enc, mask, cstab, maskf);
        hipLaunchKernelGGL(tw3_kernel, dim3(16, 16, 3), dim3(256), 0, stream, Wq, Wk, Wv, wtQ, wtK, wtV);
        hipLaunchKernelGGL(proj_v5, dim3(64, 24), dim3(256), 0, stream,
                           query, key, value, wtQ, wtK, wtV, bq, bk, bv, cstab, qws, kws, vtws);
        hipLaunchKernelGGL(attn_v9, dim3(1024), dim3(512), 0, stream,
                           qws, kws, vtws, maskf, ows);
        hipLaunchKernelGGL(tw_kernel, dim3(16, 16), dim3(256), 0, stream, Wo, wtO);
        hipLaunchKernelGGL(gemm_out_v2, dim3(64, 8), dim3(256), 0, stream, ows, wtO, bo, out);
    }
}

// Round 13
// 213.639 us; speedup vs baseline: 1.0633x; 1.0633x over previous
//
#include <hip/hip_runtime.h>

#define B_ 4
#define N_ 2048
#define D_ 1024
#define H_ 16
#define HD_ 64
// SCALE * log2(e): softmax runs in exp2 domain
#define QSCALE_ 0.18033688011112042f

typedef __bf16 bf16x8 __attribute__((ext_vector_type(8)));
typedef float f32x4 __attribute__((ext_vector_type(4)));

#if __has_builtin(__builtin_amdgcn_exp2f)
#define EXP2(x) __builtin_amdgcn_exp2f(x)
#else
#define EXP2(x) exp2f(x)
#endif

__device__ __forceinline__ f32x4 mfma16(bf16x8 a, bf16x8 b, f32x4 c) {
    return __builtin_amdgcn_mfma_f32_16x16x32_bf16(a, b, c, 0, 0, 0);
}

__device__ __forceinline__ void gload16(const void* g, void* l) {
    __builtin_amdgcn_global_load_lds(
        (const __attribute__((address_space(1))) void*)g,
        (__attribute__((address_space(3))) void*)l, 16, 0, 0);
}

__device__ __forceinline__ unsigned pack2(float x, float y) {
    __bf16 a = (__bf16)x, b = (__bf16)y;
    unsigned ua = __builtin_bit_cast(unsigned short, a);
    unsigned ub = __builtin_bit_cast(unsigned short, b);
    return ua | (ub << 16);
}

// ---------------------------------------------------------------- fused pre-pass (big path)
__global__ __launch_bounds__(256) void pre_kernel(
    const float* __restrict__ q, const float* __restrict__ k, const float* __restrict__ v,
    __bf16* __restrict__ xb,
    const float* __restrict__ W0, const float* __restrict__ W1,
    const float* __restrict__ W2, const float* __restrict__ W3,
    __bf16* __restrict__ T0, __bf16* __restrict__ T1,
    __bf16* __restrict__ T2, __bf16* __restrict__ T3,
    const float* __restrict__ pe, const int* __restrict__ mask,
    unsigned* __restrict__ cstab, float* __restrict__ maskf)
{
    const int y = blockIdx.y;
    const int x = blockIdx.x;
    const int t = threadIdx.x;

    if (y < 3) {
        const float* src = (y == 0) ? q : (y == 1) ? k : v;
        __bf16* dst = xb + (size_t)y * 8388608;
        size_t i = ((size_t)x * 256 + t) * 8;
        float4 a = *(const float4*)(src + i);
        float4 b = *(const float4*)(src + i + 4);
        bf16x8 o;
        o[0] = (__bf16)a.x; o[1] = (__bf16)a.y; o[2] = (__bf16)a.z; o[3] = (__bf16)a.w;
        o[4] = (__bf16)b.x; o[5] = (__bf16)b.y; o[6] = (__bf16)b.z; o[7] = (__bf16)b.w;
        *(bf16x8*)(dst + i) = o;
        return;
    }
    if (x < 1024) {
        const int which = x >> 8;
        const float* W = (which == 0) ? W0 : (which == 1) ? W1 : (which == 2) ? W2 : W3;
        __bf16* Wt = (which == 0) ? T0 : (which == 1) ? T1 : (which == 2) ? T2 : T3;
        const int k0 = ((x >> 4) & 15) * 64, n0 = (x & 15) * 64;
        __shared__ float T[64][65];
#pragma unroll
        for (int i = 0; i < 4; ++i) {
            int row = i * 16 + (t >> 4);
            int c4 = (t & 15) * 4;
            float4 vv = *(const float4*)(W + (size_t)(k0 + row) * D_ + n0 + c4);
            T[row][c4] = vv.x; T[row][c4 + 1] = vv.y; T[row][c4 + 2] = vv.z; T[row][c4 + 3] = vv.w;
        }
        __syncthreads();
#pragma unroll
        for (int i = 0; i < 2; ++i) {
            int task = i * 256 + t;
            int nrow = task >> 3, ks = task & 7;
            bf16x8 o;
#pragma unroll
            for (int e = 0; e < 8; ++e) o[e] = (__bf16)T[ks * 8 + e][nrow];
            *(bf16x8*)(Wt + (size_t)(n0 + nrow) * D_ + k0 + ks * 8) = o;
        }
        return;
    }
    if (x < 1568) {
        int i = (x - 1024) * 256 + t;
        if (i < N_ * HD_) {
            float vv = pe[i];
            __bf16 cb = (__bf16)cosf(vv), sb = (__bf16)sinf(vv);
            unsigned cu = __builtin_bit_cast(unsigned short, cb);
            unsigned su = __builtin_bit_cast(unsigned short, sb);
            cstab[i] = cu | (su << 16);
        }
        if (i < B_ * N_) maskf[i] = mask[i] ? -1e30f : 0.0f;
    }
}

// ---------------------------------------------------------------- prep (fallback path)
__global__ void prep_kernel(const float* __restrict__ pe, const int* __restrict__ mask,
                            unsigned* __restrict__ cstab, float* __restrict__ maskf) {
    int i = blockIdx.x * 256 + threadIdx.x;
    if (i < N_ * HD_) {
        float v = pe[i];
        __bf16 cb = (__bf16)cosf(v), sb = (__bf16)sinf(v);
        unsigned cu = __builtin_bit_cast(unsigned short, cb);
        unsigned su = __builtin_bit_cast(unsigned short, sb);
        cstab[i] = cu | (su << 16);
    }
    if (i < B_ * N_) maskf[i] = mask[i] ? -1e30f : 0.0f;
}

// ---------------------------------------------------------------- weight transpose (fallback)
__global__ __launch_bounds__(256) void tw_kernel(const float* __restrict__ W, __bf16* __restrict__ Wt) {
    __shared__ float T[64][65];
    const int k0 = blockIdx.x * 64, n0 = blockIdx.y * 64;
    const int t = threadIdx.x;
#pragma unroll
    for (int i = 0; i < 4; ++i) {
        int row = i * 16 + (t >> 4);
        int c4 = (t & 15) * 4;
        float4 v = *(const float4*)(W + (size_t)(k0 + row) * D_ + n0 + c4);
        T[row][c4] = v.x; T[row][c4 + 1] = v.y; T[row][c4 + 2] = v.z; T[row][c4 + 3] = v.w;
    }
    __syncthreads();
#pragma unroll
    for (int i = 0; i < 2; ++i) {
        int task = i * 256 + t;
        int nrow = task >> 3, ks = task & 7;
        bf16x8 o;
#pragma unroll
        for (int e = 0; e < 8; ++e) o[e] = (__bf16)T[ks * 8 + e][nrow];
        *(bf16x8*)(Wt + (size_t)(n0 + nrow) * D_ + k0 + ks * 8) = o;
    }
}

// ---------------------------------------------------------------- weight transpose x3 (fallback)
__global__ __launch_bounds__(256) void tw3_kernel(
    const float* __restrict__ W0, const float* __restrict__ W1, const float* __restrict__ W2,
    __bf16* __restrict__ T0, __bf16* __restrict__ T1, __bf16* __restrict__ T2)
{
    const float* W = (blockIdx.z == 0) ? W0 : (blockIdx.z == 1) ? W1 : W2;
    __bf16* Wt = (blockIdx.z == 0) ? T0 : (blockIdx.z == 1) ? T1 : T2;
    __shared__ float T[64][65];
    const int k0 = blockIdx.x * 64, n0 = blockIdx.y * 64;
    const int t = threadIdx.x;
#pragma unroll
    for (int i = 0; i < 4; ++i) {
        int row = i * 16 + (t >> 4);
        int c4 = (t & 15) * 4;
        float4 v = *(const float4*)(W + (size_t)(k0 + row) * D_ + n0 + c4);
        T[row][c4] = v.x; T[row][c4 + 1] = v.y; T[row][c4 + 2] = v.z; T[row][c4 + 3] = v.w;
    }
    __syncthreads();
#pragma unroll
    for (int i = 0; i < 2; ++i) {
        int task = i * 256 + t;
        int nrow = task >> 3, ks = task & 7;
        bf16x8 o;
#pragma unroll
        for (int e = 0; e < 8; ++e) o[e] = (__bf16)T[ks * 8 + e][nrow];
        *(bf16x8*)(Wt + (size_t)(n0 + nrow) * D_ + k0 + ks * 8) = o;
    }
}

// ---------------------------------------------------------------- fused QKV projection v6 (big path)
__global__ __launch_bounds__(256) void proj_v6(
    const __bf16* __restrict__ Xb,   // [3][8192][1024] bf16
    const __bf16* __restrict__ WtQ, const __bf16* __restrict__ WtK, const __bf16* __restrict__ WtV,
    const float* __restrict__ bQ, const float* __restrict__ bK, const float* __restrict__ bV,
    const unsigned* __restrict__ cstab,
    __bf16* __restrict__ dq, __bf16* __restrict__ dk, __bf16* __restrict__ dv)
{
    __shared__ __align__(16) char smem[35072];     // As 16K | Bs 16K ; mode2 epi: T[128][136]
    __bf16* As = (__bf16*)smem;
    __bf16* Bs = (__bf16*)(smem + 16384);

    const int which = blockIdx.y >> 3;
    const __bf16* X   = Xb + (size_t)which * 8388608;
    const __bf16* Wt  = (which == 0) ? WtQ : (which == 1) ? WtK : WtV;
    const float* bias = (which == 0) ? bQ  : (which == 1) ? bK  : bV;
    __bf16* dst       = (which == 0) ? dq  : (which == 1) ? dk  : dv;
    const int mode = which;

    const int tid = threadIdx.x;
    const int lane = tid & 63, w = tid >> 6;
    const int wr = w >> 1, wc = w & 1;
    const int r16 = lane & 15, g = lane >> 4;
    const int m0 = blockIdx.x * 128;
    const int n0 = (blockIdx.y & 7) * 128;
    const int srow8 = tid >> 3, slot = tid & 7;

    f32x4 acc[4][4];
#pragma unroll
    for (int m = 0; m < 4; ++m)
#pragma unroll
        for (int n = 0; n < 4; ++n) acc[m][n] = (f32x4){0.f, 0.f, 0.f, 0.f};

    for (int kt = 0; kt < 16; ++kt) {
#pragma unroll
        for (int j = 0; j < 4; ++j) {
            int row = j * 32 + srow8;
            const char* srcA = (const char*)X + ((size_t)(m0 + row) * D_ + kt * 64) * 2
                               + ((slot ^ (row & 7)) << 4);
            gload16(srcA, (char*)As + j * 4096 + w * 1024);
            const char* srcB = (const char*)Wt + ((size_t)(n0 + row) * D_ + kt * 64) * 2
                               + ((slot ^ (row & 7)) << 4);
            gload16(srcB, (char*)Bs + j * 4096 + w * 1024);
        }
        __syncthreads();
#pragma unroll
        for (int kk = 0; kk < 2; ++kk) {
            bf16x8 aF[4], bF[4];
#pragma unroll
            for (int m = 0; m < 4; ++m) {
                int row = wr * 64 + m * 16 + r16;
                aF[m] = *(const bf16x8*)((char*)As + row * 128 + (((kk * 4 + g) ^ (row & 7)) << 4));
            }
#pragma unroll
            for (int n = 0; n < 4; ++n) {
                int row = wc * 64 + n * 16 + r16;
                bF[n] = *(const bf16x8*)((char*)Bs + row * 128 + (((kk * 4 + g) ^ (row & 7)) << 4));
            }
#pragma unroll
            for (int m = 0; m < 4; ++m)
#pragma unroll
                for (int n = 0; n < 4; ++n)
                    acc[m][n] = mfma16(aF[m], bF[n], acc[m][n]);
        }
        __syncthreads();
    }

    if (mode <= 1) {
#pragma unroll
        for (int m = 0; m < 4; ++m)
#pragma unroll
            for (int n = 0; n < 4; ++n) {
                int col = n0 + wc * 64 + n * 16 + r16;
                int h = col >> 6, hd = col & 63;
#pragma unroll
                for (int j = 0; j < 4; ++j) {
                    int bn = m0 + wr * 64 + m * 16 + g * 4 + j;
                    int np = bn & (N_ - 1), b = bn >> 11;
                    float val = acc[m][n][j] + bias[col];
                    if (mode == 0) val *= QSCALE_;
                    float other = __shfl_xor(val, 1);
                    unsigned cs = cstab[np * HD_ + hd];
                    float c = __uint_as_float(cs << 16);
                    float sn = __uint_as_float(cs & 0xffff0000u);
                    val = val * c + ((col & 1) ? other : -other) * sn;
                    dst[((size_t)(b * H_ + h) * N_ + np) * HD_ + hd] = (__bf16)val;
                }
            }
    } else {
        __bf16* T = (__bf16*)smem;   // [128][136]
        __syncthreads();
#pragma unroll
        for (int m = 0; m < 4; ++m)
#pragma unroll
            for (int n = 0; n < 4; ++n) {
                int c = wc * 64 + n * 16 + r16;
                float bs = bias[n0 + c];
#pragma unroll
                for (int j = 0; j < 4; ++j) {
                    int sr = wr * 64 + m * 16 + g * 4 + j;
                    T[c * 136 + sr] = (__bf16)(acc[m][n][j] + bs);
                }
            }
        __syncthreads();
        const int b = m0 >> 11, np0 = m0 & (N_ - 1);
#pragma unroll
        for (int i = 0; i < 8; ++i) {
            int task = i * 256 + tid;
            int trow = task >> 4, ch = task & 15;
            int colg = n0 + trow;
            int h = colg >> 6, hd = colg & 63;
            bf16x8 vv = *(const bf16x8*)&T[trow * 136 + ch * 8];
            *(bf16x8*)(dst + (((size_t)(b * H_ + h) * HD_ + hd) * N_ + np0 + ch * 8)) = vv;
        }
    }
}

// ---------------------------------------------------------------- fused QKV projection v5 (fallback)
__global__ __launch_bounds__(256) void proj_v5(
    const float* __restrict__ Xq, const float* __restrict__ Xk, const float* __restrict__ Xv,
    const __bf16* __restrict__ WtQ, const __bf16* __restrict__ WtK, const __bf16* __restrict__ WtV,
    const float* __restrict__ bQ, const float* __restrict__ bK, const float* __restrict__ bV,
    const unsigned* __restrict__ cstab,
    __bf16* __restrict__ dq, __bf16* __restrict__ dk, __bf16* __restrict__ dv)
{
    __shared__ __align__(16) char smem[35072];
    __bf16* As = (__bf16*)smem;
    __bf16* Bs = (__bf16*)(smem + 16384);

    const int which = blockIdx.y >> 3;
    const float* X    = (which == 0) ? Xq  : (which == 1) ? Xk  : Xv;
    const __bf16* Wt  = (which == 0) ? WtQ : (which == 1) ? WtK : WtV;
    const float* bias = (which == 0) ? bQ  : (which == 1) ? bK  : bV;
    __bf16* dst       = (which == 0) ? dq  : (which == 1) ? dk  : dv;
    const int mode = which;

    const int tid = threadIdx.x;
    const int lane = tid & 63, w = tid >> 6;
    const int wr = w >> 1, wc = w & 1;
    const int r16 = lane & 15, g = lane >> 4;
    const int m0 = blockIdx.x * 128;
    const int n0 = (blockIdx.y & 7) * 128;
    const int srow8 = tid >> 3, slot = tid & 7;

    f32x4 acc[4][4];
#pragma unroll
    for (int m = 0; m < 4; ++m)
#pragma unroll
        for (int n = 0; n < 4; ++n) acc[m][n] = (f32x4){0.f, 0.f, 0.f, 0.f};

    for (int kt = 0; kt < 16; ++kt) {
        float4 va0[4], va1[4];
#pragma unroll
        for (int i = 0; i < 4; ++i) {
            int row = i * 32 + srow8;
            const float* s = X + (size_t)(m0 + row) * D_ + kt * 64 + slot * 8;
            va0[i] = *(const float4*)s;
            va1[i] = *(const float4*)(s + 4);
        }
#pragma unroll
        for (int j = 0; j < 4; ++j) {
            int row = j * 32 + srow8;
            const char* src = (const char*)Wt + ((size_t)(n0 + row) * D_ + kt * 64) * 2
                              + ((slot ^ (row & 7)) << 4);
            gload16(src, (char*)Bs + j * 4096 + w * 1024);
        }
#pragma unroll
        for (int i = 0; i < 4; ++i) {
            int row = i * 32 + srow8;
            bf16x8 bv;
            bv[0] = (__bf16)va0[i].x; bv[1] = (__bf16)va0[i].y;
            bv[2] = (__bf16)va0[i].z; bv[3] = (__bf16)va0[i].w;
            bv[4] = (__bf16)va1[i].x; bv[5] = (__bf16)va1[i].y;
            bv[6] = (__bf16)va1[i].z; bv[7] = (__bf16)va1[i].w;
            *(bf16x8*)((char*)As + row * 128 + ((slot ^ (row & 7)) << 4)) = bv;
        }
        __syncthreads();
#pragma unroll
        for (int kk = 0; kk < 2; ++kk) {
            bf16x8 aF[4], bF[4];
#pragma unroll
            for (int m = 0; m < 4; ++m) {
                int row = wr * 64 + m * 16 + r16;
                aF[m] = *(const bf16x8*)((char*)As + row * 128 + (((kk * 4 + g) ^ (row & 7)) << 4));
            }
#pragma unroll
            for (int n = 0; n < 4; ++n) {
                int row = wc * 64 + n * 16 + r16;
                bF[n] = *(const bf16x8*)((char*)Bs + row * 128 + (((kk * 4 + g) ^ (row & 7)) << 4));
            }
#pragma unroll
            for (int m = 0; m < 4; ++m)
#pragma unroll
                for (int n = 0; n < 4; ++n)
                    acc[m][n] = mfma16(aF[m], bF[n], acc[m][n]);
        }
        __syncthreads();
    }

    if (mode <= 1) {
#pragma unroll
        for (int m = 0; m < 4; ++m)
#pragma unroll
            for (int n = 0; n < 4; ++n) {
                int col = n0 + wc * 64 + n * 16 + r16;
                int h = col >> 6, hd = col & 63;
#pragma unroll
                for (int j = 0; j < 4; ++j) {
                    int bn = m0 + wr * 64 + m * 16 + g * 4 + j;
                    int np = bn & (N_ - 1), b = bn >> 11;
                    float val = acc[m][n][j] + bias[col];
                    if (mode == 0) val *= QSCALE_;
                    float other = __shfl_xor(val, 1);
                    unsigned cs = cstab[np * HD_ + hd];
                    float c = __uint_as_float(cs << 16);
                    float sn = __uint_as_float(cs & 0xffff0000u);
                    val = val * c + ((col & 1) ? other : -other) * sn;
                    dst[((size_t)(b * H_ + h) * N_ + np) * HD_ + hd] = (__bf16)val;
                }
            }
    } else {
        __bf16* T = (__bf16*)smem;   // [128][136]
        __syncthreads();
#pragma unroll
        for (int m = 0; m < 4; ++m)
#pragma unroll
            for (int n = 0; n < 4; ++n) {
                int c = wc * 64 + n * 16 + r16;
                float bs = bias[n0 + c];
#pragma unroll
                for (int j = 0; j < 4; ++j) {
                    int sr = wr * 64 + m * 16 + g * 4 + j;
                    T[c * 136 + sr] = (__bf16)(acc[m][n][j] + bs);
                }
            }
        __syncthreads();
        const int b = m0 >> 11, np0 = m0 & (N_ - 1);
#pragma unroll
        for (int i = 0; i < 8; ++i) {
            int task = i * 256 + tid;
            int trow = task >> 4, ch = task & 15;
            int colg = n0 + trow;
            int h = colg >> 6, hd = colg & 63;
            bf16x8 vv = *(const bf16x8*)&T[trow * 136 + ch * 8];
            *(bf16x8*)(dst + (((size_t)(b * H_ + h) * HD_ + hd) * N_ + np0 + ch * 8)) = vv;
        }
    }
}

// ---------------------------------------------------------------- flash attention v8b
// = R10's attn_v8 (best measured: 88 us) + b64 P-writes from v9 (verified layout).
// QBLK=256, 8 waves x 32 q-rows, 512 blocks, LDS 48KB.
__global__ __launch_bounds__(512, 4) void attn_v8b(
    const __bf16* __restrict__ qws, const __bf16* __restrict__ kws,
    const __bf16* __restrict__ vtws, const float* __restrict__ maskf,
    __bf16* __restrict__ ows)
{
    __shared__ __align__(16) __bf16 Ks0[4096], Ks1[4096];   // [seq 64][hd 64] swizzled
    __shared__ __align__(16) __bf16 Vs0[4096], Vs1[4096];   // [hd 64][seq 64] swizzled
    __shared__ __align__(16) char Pbuf[16384];              // 8 waves x [16 q][64 k] bf16

    const int tid = threadIdx.x;
    const int lane = tid & 63, w = tid >> 6;
    const int r16 = lane & 15, g = lane >> 4;

    // XCD swizzle: 512 blocks -> 8 chunks of 64 (8 bh each), chunk c on XCD c.
    const int lid = blockIdx.x;
    const int virt = (lid & 7) * 64 + (lid >> 3);
    const int bh = virt >> 3;
    const int b = bh >> 4, h = bh & 15;
    const int q0 = (virt & 7) * 256;
    const int srow8 = tid >> 3, slot = tid & 7;   // srow8 in [0,64)

    bf16x8 qF[2][2];
#pragma unroll
    for (int qq = 0; qq < 2; ++qq) {
        const __bf16* qb = qws + ((size_t)bh * N_ + q0 + w * 32 + qq * 16 + r16) * HD_ + g * 8;
        qF[qq][0] = *(const bf16x8*)qb;
        qF[qq][1] = *(const bf16x8*)(qb + 32);
    }

    bf16x8 onesF;
#pragma unroll
    for (int e = 0; e < 8; ++e) onesF[e] = (__bf16)1.0f;

    const char* kbase = (const char*)(kws + (size_t)bh * N_ * HD_);
    const char* vbase = (const char*)(vtws + (size_t)bh * HD_ * N_);
    const float* mbase = maskf + b * N_;
    char* Pw = Pbuf + w * 2048;

    f32x4 o[2][4];
    f32x4 lacc[2];
#pragma unroll
    for (int qq = 0; qq < 2; ++qq) {
        lacc[qq] = (f32x4){0.f, 0.f, 0.f, 0.f};
#pragma unroll
        for (int n = 0; n < 4; ++n) o[qq][n] = (f32x4){0.f, 0.f, 0.f, 0.f};
    }

// 512 threads: each issues exactly 1 K-row-slot + 1 V-row-slot gload16.
// Wave w's lanes cover rows [w*8, w*8+8) -> LDS chunk w*1024 (linear dest).
#define STAGE_(KD, VD, kt) {                                                          \
    gload16(kbase + (size_t)((kt) * 64 + srow8) * 128 + ((slot ^ (srow8 & 7)) << 4),  \
            (char*)(KD) + w * 1024);                                                  \
    gload16(vbase + (size_t)srow8 * (N_ * 2) + (kt) * 128 + ((slot ^ (srow8 & 7)) << 4), \
            (char*)(VD) + w * 1024);                                                  \
    }

#define TILE_(KB, VB, KN, VN, kt) {                                                   \
    if ((kt) + 1 < 32) STAGE_(KN, VN, (kt) + 1);                                      \
    f32x4 s0[4], s1[4];                                                               \
    _Pragma("unroll")                                                                 \
    for (int n = 0; n < 4; ++n) {                                                     \
        f32x4 mb = *(const f32x4*)(mbase + (kt) * 64 + n * 16 + g * 4);               \
        s0[n] = mb; s1[n] = mb;                                                       \
    }                                                                                 \
    __builtin_amdgcn_s_setprio(1);                                                    \
    _Pragma("unroll")                                                                 \
    for (int n = 0; n < 4; ++n) {                                                     \
        int row = n * 16 + r16;                                                       \
        bf16x8 kF0 = *(const bf16x8*)((const char*)(KB) + row * 128 + ((g ^ (row & 7)) << 4));        \
        bf16x8 kF1 = *(const bf16x8*)((const char*)(KB) + row * 128 + (((4 + g) ^ (row & 7)) << 4));  \
        s0[n] = mfma16(kF0, qF[0][0], s0[n]);                                         \
        s0[n] = mfma16(kF1, qF[0][1], s0[n]);                                         \
        s1[n] = mfma16(kF0, qF[1][0], s1[n]);                                         \
        s1[n] = mfma16(kF1, qF[1][1], s1[n]);                                         \
    }                                                                                 \
    __builtin_amdgcn_s_setprio(0);                                                    \
    bf16x8 pF0[2], pF1[2];                                                            \
    _Pragma("unroll")                                                                 \
    for (int n = 0; n < 4; ++n) {                                                     \
        int u0 = ((n * 2 + (g >> 1)) ^ (r16 & 7));                                    \
        unsigned lo = pack2(EXP2(s0[n][0]), EXP2(s0[n][1]));                          \
        unsigned hi = pack2(EXP2(s0[n][2]), EXP2(s0[n][3]));                          \
        *(unsigned long long*)(Pw + r16 * 128 + u0 * 16 + (g & 1) * 8) =              \
            ((unsigned long long)hi << 32) | lo;                                      \
    }                                                                                 \
    _Pragma("unroll")                                                                 \
    for (int kk = 0; kk < 2; ++kk)                                                    \
        pF0[kk] = *(const bf16x8*)(Pw + r16 * 128 + (((kk * 4 + g) ^ (r16 & 7)) << 4)); \
    lacc[0] = mfma16(onesF, pF0[0], lacc[0]);                                         \
    lacc[0] = mfma16(onesF, pF0[1], lacc[0]);                                         \
    _Pragma("unroll")                                                                 \
    for (int n = 0; n < 4; ++n) {                                                     \
        int u0 = ((n * 2 + (g >> 1)) ^ (r16 & 7));                                    \
        unsigned lo = pack2(EXP2(s1[n][0]), EXP2(s1[n][1]));                          \
        unsigned hi = pack2(EXP2(s1[n][2]), EXP2(s1[n][3]));                          \
        *(unsigned long long*)(Pw + r16 * 128 + u0 * 16 + (g & 1) * 8) =              \
            ((unsigned long long)hi << 32) | lo;                                      \
    }                                                                                 \
    _Pragma("unroll")                                                                 \
    for (int kk = 0; kk < 2; ++kk)                                                    \
        pF1[kk] = *(const bf16x8*)(Pw + r16 * 128 + (((kk * 4 + g) ^ (r16 & 7)) << 4)); \
    lacc[1] = mfma16(onesF, pF1[0], lacc[1]);                                         \
    lacc[1] = mfma16(onesF, pF1[1], lacc[1]);                                         \
    __builtin_amdgcn_s_setprio(1);                                                    \
    _Pragma("unroll")                                                                 \
    for (int n = 0; n < 4; ++n) {                                                     \
        int row = n * 16 + r16;                                                       \
        bf16x8 vF0 = *(const bf16x8*)((const char*)(VB) + row * 128 + ((g ^ (row & 7)) << 4));        \
        bf16x8 vF1 = *(const bf16x8*)((const char*)(VB) + row * 128 + (((4 + g) ^ (row & 7)) << 4));  \
        o[0][n] = mfma16(vF0, pF0[0], o[0][n]);                                       \
        o[0][n] = mfma16(vF1, pF0[1], o[0][n]);                                       \
        o[1][n] = mfma16(vF0, pF1[0], o[1][n]);                                       \
        o[1][n] = mfma16(vF1, pF1[1], o[1][n]);                                       \
    }                                                                                 \
    __builtin_amdgcn_s_setprio(0);                                                    \
    __syncthreads(); }

    STAGE_(Ks0, Vs0, 0);
    __syncthreads();

    for (int kt = 0; kt < 32; kt += 2) {
        TILE_(Ks0, Vs0, Ks1, Vs1, kt);
        TILE_(Ks1, Vs1, Ks0, Vs0, kt + 1);
    }
#undef TILE_
#undef STAGE_

    // epilogue: normalize, transpose O^T->O via Pbuf, 16B stores
#pragma unroll
    for (int qq = 0; qq < 2; ++qq) {
        float inv = 1.0f / lacc[qq][0];
#pragma unroll
        for (int n = 0; n < 4; ++n) {
            int u0 = ((n * 2 + (g >> 1)) ^ (r16 & 7));
            unsigned lo = pack2(o[qq][n][0] * inv, o[qq][n][1] * inv);
            unsigned hi = pack2(o[qq][n][2] * inv, o[qq][n][3] * inv);
            *(unsigned long long*)(Pw + r16 * 128 + u0 * 16 + (g & 1) * 8) =
                ((unsigned long long)hi << 32) | lo;
        }
        int qrow = q0 + w * 32 + qq * 16 + r16;
#pragma unroll
        for (int kk = 0; kk < 2; ++kk) {
            bf16x8 v = *(const bf16x8*)(Pw + r16 * 128 + (((kk * 4 + g) ^ (r16 & 7)) << 4));
            *(bf16x8*)(ows + ((size_t)(b * N_ + qrow)) * D_ + h * HD_ + kk * 32 + g * 8) = v;
        }
    }
}

// ---------------------------------------------------------------- output GEMM
__global__ __launch_bounds__(256) void gemm_out_v2(
    const __bf16* __restrict__ A, const __bf16* __restrict__ Wt,
    const float* __restrict__ bias, float* __restrict__ out)
{
    __shared__ __align__(16) __bf16 As[8192], Bs[8192];

    const int tid = threadIdx.x;
    const int lane = tid & 63, w = tid >> 6;
    const int wr = w >> 1, wc = w & 1;
    const int r16 = lane & 15, g = lane >> 4;
    const int m0 = blockIdx.x * 128;
    const int n0 = blockIdx.y * 128;
    const int srow8 = tid >> 3, slot = tid & 7;

    f32x4 acc[4][4];
#pragma unroll
    for (int m = 0; m < 4; ++m)
#pragma unroll
        for (int n = 0; n < 4; ++n) acc[m][n] = (f32x4){0.f, 0.f, 0.f, 0.f};

    for (int kt = 0; kt < 16; ++kt) {
#pragma unroll
        for (int j = 0; j < 4; ++j) {
            int row = j * 32 + srow8;
            const char* srcA = (const char*)A + ((size_t)(m0 + row) * D_ + kt * 64) * 2
                               + ((slot ^ (row & 7)) << 4);
            gload16(srcA, (char*)As + j * 4096 + w * 1024);
            const char* srcB = (const char*)Wt + ((size_t)(n0 + row) * D_ + kt * 64) * 2
                               + ((slot ^ (row & 7)) << 4);
            gload16(srcB, (char*)Bs + j * 4096 + w * 1024);
        }
        __syncthreads();
#pragma unroll
        for (int kk = 0; kk < 2; ++kk) {
            bf16x8 aF[4], bF[4];
#pragma unroll
            for (int m = 0; m < 4; ++m) {
                int row = wr * 64 + m * 16 + r16;
                aF[m] = *(const bf16x8*)((char*)As + row * 128 + (((kk * 4 + g) ^ (row & 7)) << 4));
            }
#pragma unroll
            for (int n = 0; n < 4; ++n) {
                int row = wc * 64 + n * 16 + r16;
                bF[n] = *(const bf16x8*)((char*)Bs + row * 128 + (((kk * 4 + g) ^ (row & 7)) << 4));
            }
#pragma unroll
            for (int m = 0; m < 4; ++m)
#pragma unroll
                for (int n = 0; n < 4; ++n)
                    acc[m][n] = mfma16(aF[m], bF[n], acc[m][n]);
        }
        __syncthreads();
    }

#pragma unroll
    for (int m = 0; m < 4; ++m)
#pragma unroll
        for (int n = 0; n < 4; ++n) {
            int col = n0 + wc * 64 + n * 16 + r16;
            float bs = bias[col];
#pragma unroll
            for (int j = 0; j < 4; ++j) {
                int bn = m0 + wr * 64 + m * 16 + g * 4 + j;
                out[(size_t)bn * D_ + col] = acc[m][n][j] + bs;
            }
        }
}

// ---------------------------------------------------------------- launcher
extern "C" void kernel_launch(void* const* d_in, const int* in_sizes, int n_in,
                              void* d_out, int out_size, void* d_ws, size_t ws_size,
                              hipStream_t stream)
{
    const float* query = (const float*)d_in[0];
    const float* key   = (const float*)d_in[1];
    const float* value = (const float*)d_in[2];
    const int* mask    = (const int*)d_in[3];
    const float* pos_enc = (const float*)d_in[4];
    const float* Wq = (const float*)d_in[5];
    const float* bq = (const float*)d_in[6];
    const float* Wk = (const float*)d_in[7];
    const float* bk = (const float*)d_in[8];
    const float* Wv = (const float*)d_in[9];
    const float* bv = (const float*)d_in[10];
    const float* Wo = (const float*)d_in[11];
    const float* bo = (const float*)d_in[12];
    float* out = (float*)d_out;

    char* ws = (char*)d_ws;
    const size_t MB16 = (size_t)16 * 1024 * 1024;
    const size_t MB2  = (size_t)2 * 1024 * 1024;
    const size_t need_big = 3 * MB16 + 4 * MB16 + 4 * MB2 + 524288 + 32768;
    const size_t need_small = 4 * MB16 + 524288 + 32768;

    if (ws_size >= need_big) {
        __bf16* Xb    = (__bf16*)(ws);                     // 48 MB
        __bf16* qws   = (__bf16*)(ws + 3 * MB16);
        __bf16* kws   = (__bf16*)(ws + 4 * MB16);
        __bf16* vtws  = (__bf16*)(ws + 5 * MB16);
        __bf16* ows   = (__bf16*)(ws + 6 * MB16);
        __bf16* wtQ   = (__bf16*)(ws + 7 * MB16);
        __bf16* wtK   = (__bf16*)(ws + 7 * MB16 + MB2);
        __bf16* wtV   = (__bf16*)(ws + 7 * MB16 + 2 * MB2);
        __bf16* wtO   = (__bf16*)(ws + 7 * MB16 + 3 * MB2);
        unsigned* cstab = (unsigned*)(ws + 7 * MB16 + 4 * MB2);
        float* maskf  = (float*)(ws + 7 * MB16 + 4 * MB2 + 524288);

        hipLaunchKernelGGL(pre_kernel, dim3(4096, 4), dim3(256), 0, stream,
                           query, key, value, Xb, Wq, Wk, Wv, Wo, wtQ, wtK, wtV, wtO,
                           pos_enc, mask, cstab, maskf);
        hipLaunchKernelGGL(proj_v6, dim3(64, 24), dim3(256), 0, stream,
                           Xb, wtQ, wtK, wtV, bq, bk, bv, cstab, qws, kws, vtws);
        hipLaunchKernelGGL(attn_v8b, dim3(512), dim3(512), 0, stream,
                           qws, kws, vtws, maskf, ows);
        hipLaunchKernelGGL(gemm_out_v2, dim3(64, 8), dim3(256), 0, stream, ows, wtO, bo, out);
    } else {
        if (ws_size < need_small) return;
        __bf16* qws   = (__bf16*)(ws);
        __bf16* kws   = (__bf16*)(ws + MB16);
        __bf16* vtws  = (__bf16*)(ws + 2 * MB16);
        __bf16* ows   = (__bf16*)(ws + 3 * MB16);
        unsigned* cstab = (unsigned*)(ws + 4 * MB16);
        float* maskf  = (float*)(ws + 4 * MB16 + 524288);
        __bf16* wtQ   = (__bf16*)(ws + 3 * MB16);
        __bf16* wtK   = wtQ + (size_t)D_ * D_;
        __bf16* wtV   = wtK + (size_t)D_ * D_;
        __bf16* wtO   = (__bf16*)(ws);

        hipLaunchKernelGGL(prep_kernel, dim3(512), dim3(256), 0, stream, pos_enc, mask, cstab, maskf);
        hipLaunchKernelGGL(tw3_kernel, dim3(16, 16, 3), dim3(256), 0, stream, Wq, Wk, Wv, wtQ, wtK, wtV);
        hipLaunchKernelGGL(proj_v5, dim3(64, 24), dim3(256), 0, stream,
                           query, key, value, wtQ, wtK, wtV, bq, bk, bv, cstab, qws, kws, vtws);
        hipLaunchKernelGGL(attn_v8b, dim3(512), dim3(512), 0, stream,
                           qws, kws, vtws, maskf, ows);
        hipLaunchKernelGGL(tw_kernel, dim3(16, 16), dim3(256), 0, stream, Wo, wtO);
        hipLaunchKernelGGL(gemm_out_v2, dim3(64, 8), dim3(256), 0, stream, ows, wtO, bo, out);
    }
}

// Round 14
// 206.181 us; speedup vs baseline: 1.1018x; 1.0362x over previous
//
#include <hip/hip_runtime.h>

#define B_ 4
#define N_ 2048
#define D_ 1024
#define H_ 16
#define HD_ 64
// SCALE * log2(e): softmax runs in exp2 domain
#define QSCALE_ 0.18033688011112042f

typedef __bf16 bf16x8 __attribute__((ext_vector_type(8)));
typedef float f32x4 __attribute__((ext_vector_type(4)));

#if __has_builtin(__builtin_amdgcn_exp2f)
#define EXP2(x) __builtin_amdgcn_exp2f(x)
#else
#define EXP2(x) exp2f(x)
#endif

__device__ __forceinline__ f32x4 mfma16(bf16x8 a, bf16x8 b, f32x4 c) {
    return __builtin_amdgcn_mfma_f32_16x16x32_bf16(a, b, c, 0, 0, 0);
}

__device__ __forceinline__ void gload16(const void* g, void* l) {
    __builtin_amdgcn_global_load_lds(
        (const __attribute__((address_space(1))) void*)g,
        (__attribute__((address_space(3))) void*)l, 16, 0, 0);
}

__device__ __forceinline__ unsigned pack2(float x, float y) {
    __bf16 a = (__bf16)x, b = (__bf16)y;
    unsigned ua = __builtin_bit_cast(unsigned short, a);
    unsigned ub = __builtin_bit_cast(unsigned short, b);
    return ua | (ub << 16);
}

// ---------------------------------------------------------------- fused pre-pass (big path)
__global__ __launch_bounds__(256) void pre_kernel(
    const float* __restrict__ q, const float* __restrict__ k, const float* __restrict__ v,
    __bf16* __restrict__ xb,
    const float* __restrict__ W0, const float* __restrict__ W1,
    const float* __restrict__ W2, const float* __restrict__ W3,
    __bf16* __restrict__ T0, __bf16* __restrict__ T1,
    __bf16* __restrict__ T2, __bf16* __restrict__ T3,
    const float* __restrict__ pe, const int* __restrict__ mask,
    unsigned* __restrict__ cstab, float* __restrict__ maskf)
{
    const int y = blockIdx.y;
    const int x = blockIdx.x;
    const int t = threadIdx.x;

    if (y < 3) {
        const float* src = (y == 0) ? q : (y == 1) ? k : v;
        __bf16* dst = xb + (size_t)y * 8388608;
        size_t i = ((size_t)x * 256 + t) * 8;
        float4 a = *(const float4*)(src + i);
        float4 b = *(const float4*)(src + i + 4);
        bf16x8 o;
        o[0] = (__bf16)a.x; o[1] = (__bf16)a.y; o[2] = (__bf16)a.z; o[3] = (__bf16)a.w;
        o[4] = (__bf16)b.x; o[5] = (__bf16)b.y; o[6] = (__bf16)b.z; o[7] = (__bf16)b.w;
        *(bf16x8*)(dst + i) = o;
        return;
    }
    if (x < 1024) {
        const int which = x >> 8;
        const float* W = (which == 0) ? W0 : (which == 1) ? W1 : (which == 2) ? W2 : W3;
        __bf16* Wt = (which == 0) ? T0 : (which == 1) ? T1 : (which == 2) ? T2 : T3;
        const int k0 = ((x >> 4) & 15) * 64, n0 = (x & 15) * 64;
        __shared__ float T[64][65];
#pragma unroll
        for (int i = 0; i < 4; ++i) {
            int row = i * 16 + (t >> 4);
            int c4 = (t & 15) * 4;
            float4 vv = *(const float4*)(W + (size_t)(k0 + row) * D_ + n0 + c4);
            T[row][c4] = vv.x; T[row][c4 + 1] = vv.y; T[row][c4 + 2] = vv.z; T[row][c4 + 3] = vv.w;
        }
        __syncthreads();
#pragma unroll
        for (int i = 0; i < 2; ++i) {
            int task = i * 256 + t;
            int nrow = task >> 3, ks = task & 7;
            bf16x8 o;
#pragma unroll
            for (int e = 0; e < 8; ++e) o[e] = (__bf16)T[ks * 8 + e][nrow];
            *(bf16x8*)(Wt + (size_t)(n0 + nrow) * D_ + k0 + ks * 8) = o;
        }
        return;
    }
    if (x < 1568) {
        int i = (x - 1024) * 256 + t;
        if (i < N_ * HD_) {
            float vv = pe[i];
            __bf16 cb = (__bf16)cosf(vv), sb = (__bf16)sinf(vv);
            unsigned cu = __builtin_bit_cast(unsigned short, cb);
            unsigned su = __builtin_bit_cast(unsigned short, sb);
            cstab[i] = cu | (su << 16);
        }
        if (i < B_ * N_) maskf[i] = mask[i] ? -1e30f : 0.0f;
    }
}

// ---------------------------------------------------------------- prep (fallback path)
__global__ void prep_kernel(const float* __restrict__ pe, const int* __restrict__ mask,
                            unsigned* __restrict__ cstab, float* __restrict__ maskf) {
    int i = blockIdx.x * 256 + threadIdx.x;
    if (i < N_ * HD_) {
        float v = pe[i];
        __bf16 cb = (__bf16)cosf(v), sb = (__bf16)sinf(v);
        unsigned cu = __builtin_bit_cast(unsigned short, cb);
        unsigned su = __builtin_bit_cast(unsigned short, sb);
        cstab[i] = cu | (su << 16);
    }
    if (i < B_ * N_) maskf[i] = mask[i] ? -1e30f : 0.0f;
}

// ---------------------------------------------------------------- weight transpose (fallback)
__global__ __launch_bounds__(256) void tw_kernel(const float* __restrict__ W, __bf16* __restrict__ Wt) {
    __shared__ float T[64][65];
    const int k0 = blockIdx.x * 64, n0 = blockIdx.y * 64;
    const int t = threadIdx.x;
#pragma unroll
    for (int i = 0; i < 4; ++i) {
        int row = i * 16 + (t >> 4);
        int c4 = (t & 15) * 4;
        float4 v = *(const float4*)(W + (size_t)(k0 + row) * D_ + n0 + c4);
        T[row][c4] = v.x; T[row][c4 + 1] = v.y; T[row][c4 + 2] = v.z; T[row][c4 + 3] = v.w;
    }
    __syncthreads();
#pragma unroll
    for (int i = 0; i < 2; ++i) {
        int task = i * 256 + t;
        int nrow = task >> 3, ks = task & 7;
        bf16x8 o;
#pragma unroll
        for (int e = 0; e < 8; ++e) o[e] = (__bf16)T[ks * 8 + e][nrow];
        *(bf16x8*)(Wt + (size_t)(n0 + nrow) * D_ + k0 + ks * 8) = o;
    }
}

// ---------------------------------------------------------------- weight transpose x3 (fallback)
__global__ __launch_bounds__(256) void tw3_kernel(
    const float* __restrict__ W0, const float* __restrict__ W1, const float* __restrict__ W2,
    __bf16* __restrict__ T0, __bf16* __restrict__ T1, __bf16* __restrict__ T2)
{
    const float* W = (blockIdx.z == 0) ? W0 : (blockIdx.z == 1) ? W1 : W2;
    __bf16* Wt = (blockIdx.z == 0) ? T0 : (blockIdx.z == 1) ? T1 : T2;
    __shared__ float T[64][65];
    const int k0 = blockIdx.x * 64, n0 = blockIdx.y * 64;
    const int t = threadIdx.x;
#pragma unroll
    for (int i = 0; i < 4; ++i) {
        int row = i * 16 + (t >> 4);
        int c4 = (t & 15) * 4;
        float4 v = *(const float4*)(W + (size_t)(k0 + row) * D_ + n0 + c4);
        T[row][c4] = v.x; T[row][c4 + 1] = v.y; T[row][c4 + 2] = v.z; T[row][c4 + 3] = v.w;
    }
    __syncthreads();
#pragma unroll
    for (int i = 0; i < 2; ++i) {
        int task = i * 256 + t;
        int nrow = task >> 3, ks = task & 7;
        bf16x8 o;
#pragma unroll
        for (int e = 0; e < 8; ++e) o[e] = (__bf16)T[ks * 8 + e][nrow];
        *(bf16x8*)(Wt + (size_t)(n0 + nrow) * D_ + k0 + ks * 8) = o;
    }
}

// ---------------------------------------------------------------- fused QKV projection v6 (big path)
__global__ __launch_bounds__(256) void proj_v6(
    const __bf16* __restrict__ Xb,   // [3][8192][1024] bf16
    const __bf16* __restrict__ WtQ, const __bf16* __restrict__ WtK, const __bf16* __restrict__ WtV,
    const float* __restrict__ bQ, const float* __restrict__ bK, const float* __restrict__ bV,
    const unsigned* __restrict__ cstab,
    __bf16* __restrict__ dq, __bf16* __restrict__ dk, __bf16* __restrict__ dv)
{
    __shared__ __align__(16) char smem[35072];     // As 16K | Bs 16K ; mode2 epi: T[128][136]
    __bf16* As = (__bf16*)smem;
    __bf16* Bs = (__bf16*)(smem + 16384);

    const int which = blockIdx.y >> 3;
    const __bf16* X   = Xb + (size_t)which * 8388608;
    const __bf16* Wt  = (which == 0) ? WtQ : (which == 1) ? WtK : WtV;
    const float* bias = (which == 0) ? bQ  : (which == 1) ? bK  : bV;
    __bf16* dst       = (which == 0) ? dq  : (which == 1) ? dk  : dv;
    const int mode = which;

    const int tid = threadIdx.x;
    const int lane = tid & 63, w = tid >> 6;
    const int wr = w >> 1, wc = w & 1;
    const int r16 = lane & 15, g = lane >> 4;
    const int m0 = blockIdx.x * 128;
    const int n0 = (blockIdx.y & 7) * 128;
    const int srow8 = tid >> 3, slot = tid & 7;

    f32x4 acc[4][4];
#pragma unroll
    for (int m = 0; m < 4; ++m)
#pragma unroll
        for (int n = 0; n < 4; ++n) acc[m][n] = (f32x4){0.f, 0.f, 0.f, 0.f};

    for (int kt = 0; kt < 16; ++kt) {
#pragma unroll
        for (int j = 0; j < 4; ++j) {
            int row = j * 32 + srow8;
            const char* srcA = (const char*)X + ((size_t)(m0 + row) * D_ + kt * 64) * 2
                               + ((slot ^ (row & 7)) << 4);
            gload16(srcA, (char*)As + j * 4096 + w * 1024);
            const char* srcB = (const char*)Wt + ((size_t)(n0 + row) * D_ + kt * 64) * 2
                               + ((slot ^ (row & 7)) << 4);
            gload16(srcB, (char*)Bs + j * 4096 + w * 1024);
        }
        __syncthreads();
#pragma unroll
        for (int kk = 0; kk < 2; ++kk) {
            bf16x8 aF[4], bF[4];
#pragma unroll
            for (int m = 0; m < 4; ++m) {
                int row = wr * 64 + m * 16 + r16;
                aF[m] = *(const bf16x8*)((char*)As + row * 128 + (((kk * 4 + g) ^ (row & 7)) << 4));
            }
#pragma unroll
            for (int n = 0; n < 4; ++n) {
                int row = wc * 64 + n * 16 + r16;
                bF[n] = *(const bf16x8*)((char*)Bs + row * 128 + (((kk * 4 + g) ^ (row & 7)) << 4));
            }
#pragma unroll
            for (int m = 0; m < 4; ++m)
#pragma unroll
                for (int n = 0; n < 4; ++n)
                    acc[m][n] = mfma16(aF[m], bF[n], acc[m][n]);
        }
        __syncthreads();
    }

    if (mode <= 1) {
#pragma unroll
        for (int m = 0; m < 4; ++m)
#pragma unroll
            for (int n = 0; n < 4; ++n) {
                int col = n0 + wc * 64 + n * 16 + r16;
                int h = col >> 6, hd = col & 63;
#pragma unroll
                for (int j = 0; j < 4; ++j) {
                    int bn = m0 + wr * 64 + m * 16 + g * 4 + j;
                    int np = bn & (N_ - 1), b = bn >> 11;
                    float val = acc[m][n][j] + bias[col];
                    if (mode == 0) val *= QSCALE_;
                    float other = __shfl_xor(val, 1);
                    unsigned cs = cstab[np * HD_ + hd];
                    float c = __uint_as_float(cs << 16);
                    float sn = __uint_as_float(cs & 0xffff0000u);
                    val = val * c + ((col & 1) ? other : -other) * sn;
                    dst[((size_t)(b * H_ + h) * N_ + np) * HD_ + hd] = (__bf16)val;
                }
            }
    } else {
        __bf16* T = (__bf16*)smem;   // [128][136]
        __syncthreads();
#pragma unroll
        for (int m = 0; m < 4; ++m)
#pragma unroll
            for (int n = 0; n < 4; ++n) {
                int c = wc * 64 + n * 16 + r16;
                float bs = bias[n0 + c];
#pragma unroll
                for (int j = 0; j < 4; ++j) {
                    int sr = wr * 64 + m * 16 + g * 4 + j;
                    T[c * 136 + sr] = (__bf16)(acc[m][n][j] + bs);
                }
            }
        __syncthreads();
        const int b = m0 >> 11, np0 = m0 & (N_ - 1);
#pragma unroll
        for (int i = 0; i < 8; ++i) {
            int task = i * 256 + tid;
            int trow = task >> 4, ch = task & 15;
            int colg = n0 + trow;
            int h = colg >> 6, hd = colg & 63;
            bf16x8 vv = *(const bf16x8*)&T[trow * 136 + ch * 8];
            *(bf16x8*)(dst + (((size_t)(b * H_ + h) * HD_ + hd) * N_ + np0 + ch * 8)) = vv;
        }
    }
}

// ---------------------------------------------------------------- fused QKV projection v5 (fallback)
__global__ __launch_bounds__(256) void proj_v5(
    const float* __restrict__ Xq, const float* __restrict__ Xk, const float* __restrict__ Xv,
    const __bf16* __restrict__ WtQ, const __bf16* __restrict__ WtK, const __bf16* __restrict__ WtV,
    const float* __restrict__ bQ, const float* __restrict__ bK, const float* __restrict__ bV,
    const unsigned* __restrict__ cstab,
    __bf16* __restrict__ dq, __bf16* __restrict__ dk, __bf16* __restrict__ dv)
{
    __shared__ __align__(16) char smem[35072];
    __bf16* As = (__bf16*)smem;
    __bf16* Bs = (__bf16*)(smem + 16384);

    const int which = blockIdx.y >> 3;
    const float* X    = (which == 0) ? Xq  : (which == 1) ? Xk  : Xv;
    const __bf16* Wt  = (which == 0) ? WtQ : (which == 1) ? WtK : WtV;
    const float* bias = (which == 0) ? bQ  : (which == 1) ? bK  : bV;
    __bf16* dst       = (which == 0) ? dq  : (which == 1) ? dk  : dv;
    const int mode = which;

    const int tid = threadIdx.x;
    const int lane = tid & 63, w = tid >> 6;
    const int wr = w >> 1, wc = w & 1;
    const int r16 = lane & 15, g = lane >> 4;
    const int m0 = blockIdx.x * 128;
    const int n0 = (blockIdx.y & 7) * 128;
    const int srow8 = tid >> 3, slot = tid & 7;

    f32x4 acc[4][4];
#pragma unroll
    for (int m = 0; m < 4; ++m)
#pragma unroll
        for (int n = 0; n < 4; ++n) acc[m][n] = (f32x4){0.f, 0.f, 0.f, 0.f};

    for (int kt = 0; kt < 16; ++kt) {
        float4 va0[4], va1[4];
#pragma unroll
        for (int i = 0; i < 4; ++i) {
            int row = i * 32 + srow8;
            const float* s = X + (size_t)(m0 + row) * D_ + kt * 64 + slot * 8;
            va0[i] = *(const float4*)s;
            va1[i] = *(const float4*)(s + 4);
        }
#pragma unroll
        for (int j = 0; j < 4; ++j) {
            int row = j * 32 + srow8;
            const char* src = (const char*)Wt + ((size_t)(n0 + row) * D_ + kt * 64) * 2
                              + ((slot ^ (row & 7)) << 4);
            gload16(src, (char*)Bs + j * 4096 + w * 1024);
        }
#pragma unroll
        for (int i = 0; i < 4; ++i) {
            int row = i * 32 + srow8;
            bf16x8 bv;
            bv[0] = (__bf16)va0[i].x; bv[1] = (__bf16)va0[i].y;
            bv[2] = (__bf16)va0[i].z; bv[3] = (__bf16)va0[i].w;
            bv[4] = (__bf16)va1[i].x; bv[5] = (__bf16)va1[i].y;
            bv[6] = (__bf16)va1[i].z; bv[7] = (__bf16)va1[i].w;
            *(bf16x8*)((char*)As + row * 128 + ((slot ^ (row & 7)) << 4)) = bv;
        }
        __syncthreads();
#pragma unroll
        for (int kk = 0; kk < 2; ++kk) {
            bf16x8 aF[4], bF[4];
#pragma unroll
            for (int m = 0; m < 4; ++m) {
                int row = wr * 64 + m * 16 + r16;
                aF[m] = *(const bf16x8*)((char*)As + row * 128 + (((kk * 4 + g) ^ (row & 7)) << 4));
            }
#pragma unroll
            for (int n = 0; n < 4; ++n) {
                int row = wc * 64 + n * 16 + r16;
                bF[n] = *(const bf16x8*)((char*)Bs + row * 128 + (((kk * 4 + g) ^ (row & 7)) << 4));
            }
#pragma unroll
            for (int m = 0; m < 4; ++m)
#pragma unroll
                for (int n = 0; n < 4; ++n)
                    acc[m][n] = mfma16(aF[m], bF[n], acc[m][n]);
        }
        __syncthreads();
    }

    if (mode <= 1) {
#pragma unroll
        for (int m = 0; m < 4; ++m)
#pragma unroll
            for (int n = 0; n < 4; ++n) {
                int col = n0 + wc * 64 + n * 16 + r16;
                int h = col >> 6, hd = col & 63;
#pragma unroll
                for (int j = 0; j < 4; ++j) {
                    int bn = m0 + wr * 64 + m * 16 + g * 4 + j;
                    int np = bn & (N_ - 1), b = bn >> 11;
                    float val = acc[m][n][j] + bias[col];
                    if (mode == 0) val *= QSCALE_;
                    float other = __shfl_xor(val, 1);
                    unsigned cs = cstab[np * HD_ + hd];
                    float c = __uint_as_float(cs << 16);
                    float sn = __uint_as_float(cs & 0xffff0000u);
                    val = val * c + ((col & 1) ? other : -other) * sn;
                    dst[((size_t)(b * H_ + h) * N_ + np) * HD_ + hd] = (__bf16)val;
                }
            }
    } else {
        __bf16* T = (__bf16*)smem;   // [128][136]
        __syncthreads();
#pragma unroll
        for (int m = 0; m < 4; ++m)
#pragma unroll
            for (int n = 0; n < 4; ++n) {
                int c = wc * 64 + n * 16 + r16;
                float bs = bias[n0 + c];
#pragma unroll
                for (int j = 0; j < 4; ++j) {
                    int sr = wr * 64 + m * 16 + g * 4 + j;
                    T[c * 136 + sr] = (__bf16)(acc[m][n][j] + bs);
                }
            }
        __syncthreads();
        const int b = m0 >> 11, np0 = m0 & (N_ - 1);
#pragma unroll
        for (int i = 0; i < 8; ++i) {
            int task = i * 256 + tid;
            int trow = task >> 4, ch = task & 15;
            int colg = n0 + trow;
            int h = colg >> 6, hd = colg & 63;
            bf16x8 vv = *(const bf16x8*)&T[trow * 136 + ch * 8];
            *(bf16x8*)(dst + (((size_t)(b * H_ + h) * HD_ + hd) * N_ + np0 + ch * 8)) = vv;
        }
    }
}

// ---------------------------------------------------------------- flash attention v8 (R10 optimum, exact)
// QBLK=256, 8 waves x 32 q-rows, 512 blocks, LDS 48KB, two b32 P-writes.
__global__ __launch_bounds__(512, 4) void attn_v8(
    const __bf16* __restrict__ qws, const __bf16* __restrict__ kws,
    const __bf16* __restrict__ vtws, const float* __restrict__ maskf,
    __bf16* __restrict__ ows)
{
    __shared__ __align__(16) __bf16 Ks0[4096], Ks1[4096];   // [seq 64][hd 64] swizzled
    __shared__ __align__(16) __bf16 Vs0[4096], Vs1[4096];   // [hd 64][seq 64] swizzled
    __shared__ __align__(16) char Pbuf[16384];              // 8 waves x [16 q][64 k] bf16

    const int tid = threadIdx.x;
    const int lane = tid & 63, w = tid >> 6;
    const int r16 = lane & 15, g = lane >> 4;

    // XCD swizzle: 512 blocks -> 8 chunks of 64 (8 bh each), chunk c on XCD c.
    const int lid = blockIdx.x;
    const int virt = (lid & 7) * 64 + (lid >> 3);
    const int bh = virt >> 3;
    const int b = bh >> 4, h = bh & 15;
    const int q0 = (virt & 7) * 256;
    const int srow8 = tid >> 3, slot = tid & 7;   // srow8 in [0,64)

    bf16x8 qF[2][2];
#pragma unroll
    for (int qq = 0; qq < 2; ++qq) {
        const __bf16* qb = qws + ((size_t)bh * N_ + q0 + w * 32 + qq * 16 + r16) * HD_ + g * 8;
        qF[qq][0] = *(const bf16x8*)qb;
        qF[qq][1] = *(const bf16x8*)(qb + 32);
    }

    bf16x8 onesF;
#pragma unroll
    for (int e = 0; e < 8; ++e) onesF[e] = (__bf16)1.0f;

    const char* kbase = (const char*)(kws + (size_t)bh * N_ * HD_);
    const char* vbase = (const char*)(vtws + (size_t)bh * HD_ * N_);
    const float* mbase = maskf + b * N_;
    char* Pw = Pbuf + w * 2048;

    f32x4 o[2][4];
    f32x4 lacc[2];
#pragma unroll
    for (int qq = 0; qq < 2; ++qq) {
        lacc[qq] = (f32x4){0.f, 0.f, 0.f, 0.f};
#pragma unroll
        for (int n = 0; n < 4; ++n) o[qq][n] = (f32x4){0.f, 0.f, 0.f, 0.f};
    }

// 512 threads: each issues exactly 1 K-row-slot + 1 V-row-slot gload16.
// Wave w's lanes cover rows [w*8, w*8+8) -> LDS chunk w*1024 (linear dest).
#define STAGE_(KD, VD, kt) {                                                          \
    gload16(kbase + (size_t)((kt) * 64 + srow8) * 128 + ((slot ^ (srow8 & 7)) << 4),  \
            (char*)(KD) + w * 1024);                                                  \
    gload16(vbase + (size_t)srow8 * (N_ * 2) + (kt) * 128 + ((slot ^ (srow8 & 7)) << 4), \
            (char*)(VD) + w * 1024);                                                  \
    }

#define TILE_(KB, VB, KN, VN, kt) {                                                   \
    if ((kt) + 1 < 32) STAGE_(KN, VN, (kt) + 1);                                      \
    f32x4 s0[4], s1[4];                                                               \
    _Pragma("unroll")                                                                 \
    for (int n = 0; n < 4; ++n) {                                                     \
        f32x4 mb = *(const f32x4*)(mbase + (kt) * 64 + n * 16 + g * 4);               \
        s0[n] = mb; s1[n] = mb;                                                       \
    }                                                                                 \
    __builtin_amdgcn_s_setprio(1);                                                    \
    _Pragma("unroll")                                                                 \
    for (int n = 0; n < 4; ++n) {                                                     \
        int row = n * 16 + r16;                                                       \
        bf16x8 kF0 = *(const bf16x8*)((const char*)(KB) + row * 128 + ((g ^ (row & 7)) << 4));        \
        bf16x8 kF1 = *(const bf16x8*)((const char*)(KB) + row * 128 + (((4 + g) ^ (row & 7)) << 4));  \
        s0[n] = mfma16(kF0, qF[0][0], s0[n]);                                         \
        s0[n] = mfma16(kF1, qF[0][1], s0[n]);                                         \
        s1[n] = mfma16(kF0, qF[1][0], s1[n]);                                         \
        s1[n] = mfma16(kF1, qF[1][1], s1[n]);                                         \
    }                                                                                 \
    __builtin_amdgcn_s_setprio(0);                                                    \
    bf16x8 pF0[2], pF1[2];                                                            \
    _Pragma("unroll")                                                                 \
    for (int n = 0; n < 4; ++n) {                                                     \
        int u0 = ((n * 2 + (g >> 1)) ^ (r16 & 7));                                    \
        int off = (g & 1) * 2;                                                        \
        *(unsigned*)(Pw + r16 * 128 + u0 * 16 + off * 4)       = pack2(EXP2(s0[n][0]), EXP2(s0[n][1])); \
        *(unsigned*)(Pw + r16 * 128 + u0 * 16 + (off + 1) * 4) = pack2(EXP2(s0[n][2]), EXP2(s0[n][3])); \
    }                                                                                 \
    _Pragma("unroll")                                                                 \
    for (int kk = 0; kk < 2; ++kk)                                                    \
        pF0[kk] = *(const bf16x8*)(Pw + r16 * 128 + (((kk * 4 + g) ^ (r16 & 7)) << 4)); \
    lacc[0] = mfma16(onesF, pF0[0], lacc[0]);                                         \
    lacc[0] = mfma16(onesF, pF0[1], lacc[0]);                                         \
    _Pragma("unroll")                                                                 \
    for (int n = 0; n < 4; ++n) {                                                     \
        int u0 = ((n * 2 + (g >> 1)) ^ (r16 & 7));                                    \
        int off = (g & 1) * 2;                                                        \
        *(unsigned*)(Pw + r16 * 128 + u0 * 16 + off * 4)       = pack2(EXP2(s1[n][0]), EXP2(s1[n][1])); \
        *(unsigned*)(Pw + r16 * 128 + u0 * 16 + (off + 1) * 4) = pack2(EXP2(s1[n][2]), EXP2(s1[n][3])); \
    }                                                                                 \
    _Pragma("unroll")                                                                 \
    for (int kk = 0; kk < 2; ++kk)                                                    \
        pF1[kk] = *(const bf16x8*)(Pw + r16 * 128 + (((kk * 4 + g) ^ (r16 & 7)) << 4)); \
    lacc[1] = mfma16(onesF, pF1[0], lacc[1]);                                         \
    lacc[1] = mfma16(onesF, pF1[1], lacc[1]);                                         \
    __builtin_amdgcn_s_setprio(1);                                                    \
    _Pragma("unroll")                                                                 \
    for (int n = 0; n < 4; ++n) {                                                     \
        int row = n * 16 + r16;                                                       \
        bf16x8 vF0 = *(const bf16x8*)((const char*)(VB) + row * 128 + ((g ^ (row & 7)) << 4));        \
        bf16x8 vF1 = *(const bf16x8*)((const char*)(VB) + row * 128 + (((4 + g) ^ (row & 7)) << 4));  \
        o[0][n] = mfma16(vF0, pF0[0], o[0][n]);                                       \
        o[0][n] = mfma16(vF1, pF0[1], o[0][n]);                                       \
        o[1][n] = mfma16(vF0, pF1[0], o[1][n]);                                       \
        o[1][n] = mfma16(vF1, pF1[1], o[1][n]);                                       \
    }                                                                                 \
    __builtin_amdgcn_s_setprio(0);                                                    \
    __syncthreads(); }

    STAGE_(Ks0, Vs0, 0);
    __syncthreads();

    for (int kt = 0; kt < 32; kt += 2) {
        TILE_(Ks0, Vs0, Ks1, Vs1, kt);
        TILE_(Ks1, Vs1, Ks0, Vs0, kt + 1);
    }
#undef TILE_
#undef STAGE_

    // epilogue: normalize, transpose O^T->O via Pbuf, 16B stores
#pragma unroll
    for (int qq = 0; qq < 2; ++qq) {
        float inv = 1.0f / lacc[qq][0];
#pragma unroll
        for (int n = 0; n < 4; ++n) {
            int u0 = ((n * 2 + (g >> 1)) ^ (r16 & 7));
            int off = (g & 1) * 2;
            *(unsigned*)(Pw + r16 * 128 + u0 * 16 + off * 4)       = pack2(o[qq][n][0] * inv, o[qq][n][1] * inv);
            *(unsigned*)(Pw + r16 * 128 + u0 * 16 + (off + 1) * 4) = pack2(o[qq][n][2] * inv, o[qq][n][3] * inv);
        }
        int qrow = q0 + w * 32 + qq * 16 + r16;
#pragma unroll
        for (int kk = 0; kk < 2; ++kk) {
            bf16x8 v = *(const bf16x8*)(Pw + r16 * 128 + (((kk * 4 + g) ^ (r16 & 7)) << 4));
            *(bf16x8*)(ows + ((size_t)(b * N_ + qrow)) * D_ + h * HD_ + kk * 32 + g * 8) = v;
        }
    }
}

// ---------------------------------------------------------------- output GEMM
__global__ __launch_bounds__(256) void gemm_out_v2(
    const __bf16* __restrict__ A, const __bf16* __restrict__ Wt,
    const float* __restrict__ bias, float* __restrict__ out)
{
    __shared__ __align__(16) __bf16 As[8192], Bs[8192];

    const int tid = threadIdx.x;
    const int lane = tid & 63, w = tid >> 6;
    const int wr = w >> 1, wc = w & 1;
    const int r16 = lane & 15, g = lane >> 4;
    const int m0 = blockIdx.x * 128;
    const int n0 = blockIdx.y * 128;
    const int srow8 = tid >> 3, slot = tid & 7;

    f32x4 acc[4][4];
#pragma unroll
    for (int m = 0; m < 4; ++m)
#pragma unroll
        for (int n = 0; n < 4; ++n) acc[m][n] = (f32x4){0.f, 0.f, 0.f, 0.f};

    for (int kt = 0; kt < 16; ++kt) {
#pragma unroll
        for (int j = 0; j < 4; ++j) {
            int row = j * 32 + srow8;
            const char* srcA = (const char*)A + ((size_t)(m0 + row) * D_ + kt * 64) * 2
                               + ((slot ^ (row & 7)) << 4);
            gload16(srcA, (char*)As + j * 4096 + w * 1024);
            const char* srcB = (const char*)Wt + ((size_t)(n0 + row) * D_ + kt * 64) * 2
                               + ((slot ^ (row & 7)) << 4);
            gload16(srcB, (char*)Bs + j * 4096 + w * 1024);
        }
        __syncthreads();
#pragma unroll
        for (int kk = 0; kk < 2; ++kk) {
            bf16x8 aF[4], bF[4];
#pragma unroll
            for (int m = 0; m < 4; ++m) {
                int row = wr * 64 + m * 16 + r16;
                aF[m] = *(const bf16x8*)((char*)As + row * 128 + (((kk * 4 + g) ^ (row & 7)) << 4));
            }
#pragma unroll
            for (int n = 0; n < 4; ++n) {
                int row = wc * 64 + n * 16 + r16;
                bF[n] = *(const bf16x8*)((char*)Bs + row * 128 + (((kk * 4 + g) ^ (row & 7)) << 4));
            }
#pragma unroll
            for (int m = 0; m < 4; ++m)
#pragma unroll
                for (int n = 0; n < 4; ++n)
                    acc[m][n] = mfma16(aF[m], bF[n], acc[m][n]);
        }
        __syncthreads();
    }

#pragma unroll
    for (int m = 0; m < 4; ++m)
#pragma unroll
        for (int n = 0; n < 4; ++n) {
            int col = n0 + wc * 64 + n * 16 + r16;
            float bs = bias[col];
#pragma unroll
            for (int j = 0; j < 4; ++j) {
                int bn = m0 + wr * 64 + m * 16 + g * 4 + j;
                out[(size_t)bn * D_ + col] = acc[m][n][j] + bs;
            }
        }
}

// ---------------------------------------------------------------- launcher
extern "C" void kernel_launch(void* const* d_in, const int* in_sizes, int n_in,
                              void* d_out, int out_size, void* d_ws, size_t ws_size,
                              hipStream_t stream)
{
    const float* query = (const float*)d_in[0];
    const float* key   = (const float*)d_in[1];
    const float* value = (const float*)d_in[2];
    const int* mask    = (const int*)d_in[3];
    const float* pos_enc = (const float*)d_in[4];
    const float* Wq = (const float*)d_in[5];
    const float* bq = (const float*)d_in[6];
    const float* Wk = (const float*)d_in[7];
    const float* bk = (const float*)d_in[8];
    const float* Wv = (const float*)d_in[9];
    const float* bv = (const float*)d_in[10];
    const float* Wo = (const float*)d_in[11];
    const float* bo = (const float*)d_in[12];
    float* out = (float*)d_out;

    char* ws = (char*)d_ws;
    const size_t MB16 = (size_t)16 * 1024 * 1024;
    const size_t MB2  = (size_t)2 * 1024 * 1024;
    const size_t need_big = 3 * MB16 + 4 * MB16 + 4 * MB2 + 524288 + 32768;
    const size_t need_small = 4 * MB16 + 524288 + 32768;

    if (ws_size >= need_big) {
        __bf16* Xb    = (__bf16*)(ws);                     // 48 MB
        __bf16* qws   = (__bf16*)(ws + 3 * MB16);
        __bf16* kws   = (__bf16*)(ws + 4 * MB16);
        __bf16* vtws  = (__bf16*)(ws + 5 * MB16);
        __bf16* ows   = (__bf16*)(ws + 6 * MB16);
        __bf16* wtQ   = (__bf16*)(ws + 7 * MB16);
        __bf16* wtK   = (__bf16*)(ws + 7 * MB16 + MB2);
        __bf16* wtV   = (__bf16*)(ws + 7 * MB16 + 2 * MB2);
        __bf16* wtO   = (__bf16*)(ws + 7 * MB16 + 3 * MB2);
        unsigned* cstab = (unsigned*)(ws + 7 * MB16 + 4 * MB2);
        float* maskf  = (float*)(ws + 7 * MB16 + 4 * MB2 + 524288);

        hipLaunchKernelGGL(pre_kernel, dim3(4096, 4), dim3(256), 0, stream,
                           query, key, value, Xb, Wq, Wk, Wv, Wo, wtQ, wtK, wtV, wtO,
                           pos_enc, mask, cstab, maskf);
        hipLaunchKernelGGL(proj_v6, dim3(64, 24), dim3(256), 0, stream,
                           Xb, wtQ, wtK, wtV, bq, bk, bv, cstab, qws, kws, vtws);
        hipLaunchKernelGGL(attn_v8, dim3(512), dim3(512), 0, stream,
                           qws, kws, vtws, maskf, ows);
        hipLaunchKernelGGL(gemm_out_v2, dim3(64, 8), dim3(256), 0, stream, ows, wtO, bo, out);
    } else {
        if (ws_size < need_small) return;
        __bf16* qws   = (__bf16*)(ws);
        __bf16* kws   = (__bf16*)(ws + MB16);
        __bf16* vtws  = (__bf16*)(ws + 2 * MB16);
        __bf16* ows   = (__bf16*)(ws + 3 * MB16);
        unsigned* cstab = (unsigned*)(ws + 4 * MB16);
        float* maskf  = (float*)(ws + 4 * MB16 + 524288);
        __bf16* wtQ   = (__bf16*)(ws + 3 * MB16);
        __bf16* wtK   = wtQ + (size_t)D_ * D_;
        __bf16* wtV   = wtK + (size_t)D_ * D_;
        __bf16* wtO   = (__bf16*)(ws);

        hipLaunchKernelGGL(prep_kernel, dim3(512), dim3(256), 0, stream, pos_enc, mask, cstab, maskf);
        hipLaunchKernelGGL(tw3_kernel, dim3(16, 16, 3), dim3(256), 0, stream, Wq, Wk, Wv, wtQ, wtK, wtV);
        hipLaunchKernelGGL(proj_v5, dim3(64, 24), dim3(256), 0, stream,
                           query, key, value, wtQ, wtK, wtV, bq, bk, bv, cstab, qws, kws, vtws);
        hipLaunchKernelGGL(attn_v8, dim3(512), dim3(512), 0, stream,
                           qws, kws, vtws, maskf, ows);
        hipLaunchKernelGGL(tw_kernel, dim3(16, 16), dim3(256), 0, stream, Wo, wtO);
        hipLaunchKernelGGL(gemm_out_v2, dim3(64, 8), dim3(256), 0, stream, ows, wtO, bo, out);
    }
}